// Round 2
// baseline (17411.745 us; speedup 1.0000x reference)
//
#include <hip/hip_runtime.h>
#include <math.h>

#define T_ 8
#define N_ 20000
#define E_ 320000
#define ETOT_ (E_ + N_)
#define FIN_ 32
#define C1_ 256   // HEADS*HID
#define HID_ 64
#define G3_ 384   // 3*GH
#define GH_ 128

// ---------------- helpers ----------------
__device__ __forceinline__ float wave_sum(float v) {
#pragma unroll
  for (int off = 32; off; off >>= 1) v += __shfl_down(v, off);
  return v;
}
__device__ __forceinline__ float sigmoidf_(float x) { return 1.f / (1.f + __expf(-x)); }
__device__ __forceinline__ float tanhf_(float x) {
  float e2 = __expf(2.f * x);          // inf-safe: x>>0 -> 1, x<<0 -> -1
  return 1.f - 2.f / (e2 + 1.f);
}
__device__ __forceinline__ void edge_sd(const int* ei, int e, int& s, int& d) {
  if (e < E_) { s = ei[e]; d = ei[E_ + e]; }
  else { s = e - E_; d = e - E_; }      // self loops appended
}

// ---------------- CSR build (by dst) ----------------
__global__ void k_hist(const int* __restrict__ ei, int* __restrict__ counts) {
  int e = blockIdx.x * 256 + threadIdx.x;
  if (e >= ETOT_) return;
  int s, d; edge_sd(ei, e, s, d);
  atomicAdd(&counts[d], 1);
}

__global__ void k_scan(const int* __restrict__ counts, int* __restrict__ indptr) {
  __shared__ int tmp[1024];
  __shared__ int carry;
  int tid = threadIdx.x;
  if (tid == 0) { carry = 0; indptr[0] = 0; }
  __syncthreads();
  for (int base = 0; base < N_; base += 1024) {
    int i = base + tid;
    int v = (i < N_) ? counts[i] : 0;
    tmp[tid] = v;
    __syncthreads();
    for (int off = 1; off < 1024; off <<= 1) {
      int add = (tid >= off) ? tmp[tid - off] : 0;
      __syncthreads();
      tmp[tid] += add;
      __syncthreads();
    }
    if (i < N_) indptr[i + 1] = carry + tmp[tid];
    __syncthreads();
    if (tid == 1023) carry += tmp[1023];
    __syncthreads();
  }
}

__global__ void k_copy(const int* __restrict__ indptr, int* __restrict__ cursors) {
  int i = blockIdx.x * 256 + threadIdx.x;
  if (i < N_) cursors[i] = indptr[i];
}

__global__ void k_scatter(const int* __restrict__ ei, int* __restrict__ cursors,
                          int* __restrict__ csr_src) {
  int e = blockIdx.x * 256 + threadIdx.x;
  if (e >= ETOT_) return;
  int s, d; edge_sd(ei, e, s, d);
  int pos = atomicAdd(&cursors[d], 1);
  csr_src[pos] = s;
}

// transpose [G3_][GH_] -> [GH_][G3_]
__global__ void k_transpose(const float* __restrict__ in, float* __restrict__ out) {
  int idx = blockIdx.x * 256 + threadIdx.x;
  if (idx < G3_ * GH_) {
    int g = idx / GH_, k = idx % GH_;
    out[k * G3_ + g] = in[idx];
  }
}

// ---------------- GAT layer 1 ----------------
__global__ __launch_bounds__(256) void k_gat1_lin(
    const float* __restrict__ x, const float* __restrict__ W1,
    const float* __restrict__ as1, const float* __restrict__ ad1,
    float* __restrict__ hlin, float* __restrict__ als, float* __restrict__ ald) {
  int n = blockIdx.x;
  int j = threadIdx.x;
  __shared__ float sx[FIN_];
  if (j < FIN_) sx[j] = x[n * FIN_ + j];
  __syncthreads();
  float acc = 0.f;
#pragma unroll
  for (int k = 0; k < FIN_; ++k) acc = fmaf(sx[k], W1[k * C1_ + j], acc);
  hlin[(size_t)n * C1_ + j] = acc;
  int h = j >> 6, c = j & 63;
  float vs = wave_sum(acc * as1[h * 64 + c]);
  float vd = wave_sum(acc * ad1[h * 64 + c]);
  if (c == 0) { als[n * 4 + h] = vs; ald[n * 4 + h] = vd; }
}

__global__ __launch_bounds__(256) void k_gat1_attn(
    const int* __restrict__ csr_src, const int* __restrict__ indptr,
    const float* __restrict__ als, const float* __restrict__ ald,
    float* __restrict__ ex, float* __restrict__ sums) {
  int w = threadIdx.x >> 6, lane = threadIdx.x & 63;
  int n = blockIdx.x * 4 + w;
  int s0 = indptr[n], s1 = indptr[n + 1];
  float adv[4], mx[4], sm[4];
#pragma unroll
  for (int h = 0; h < 4; ++h) { adv[h] = ald[n * 4 + h]; mx[h] = -1e30f; sm[h] = 0.f; }
  for (int e = s0 + lane; e < s1; e += 64) {
    int s = csr_src[e];
#pragma unroll
    for (int h = 0; h < 4; ++h) {
      float sc = als[s * 4 + h] + adv[h];
      sc = sc >= 0.f ? sc : 0.2f * sc;     // leaky_relu 0.2
      ex[(size_t)e * 4 + h] = sc;
      mx[h] = fmaxf(mx[h], sc);
    }
  }
#pragma unroll
  for (int h = 0; h < 4; ++h) {
#pragma unroll
    for (int off = 32; off; off >>= 1) mx[h] = fmaxf(mx[h], __shfl_xor(mx[h], off));
  }
  for (int e = s0 + lane; e < s1; e += 64) {
#pragma unroll
    for (int h = 0; h < 4; ++h) {
      float v = __expf(ex[(size_t)e * 4 + h] - mx[h]);
      ex[(size_t)e * 4 + h] = v;
      sm[h] += v;
    }
  }
#pragma unroll
  for (int h = 0; h < 4; ++h) sm[h] = wave_sum(sm[h]);
  if (lane == 0) {
#pragma unroll
    for (int h = 0; h < 4; ++h) sums[n * 4 + h] = sm[h];
  }
}

__global__ __launch_bounds__(256) void k_gat1_agg(
    const int* __restrict__ csr_src, const int* __restrict__ indptr,
    const float* __restrict__ ex, const float* __restrict__ sums,
    const float* __restrict__ hlin, const float* __restrict__ b1,
    float* __restrict__ h1out) {
  int n = blockIdx.x;
  int j = threadIdx.x;
  int hh = j >> 6;
  int s0 = indptr[n], s1 = indptr[n + 1];
  float inv = 1.f / (sums[n * 4 + hh] + 1e-16f);
  float acc = 0.f;
  for (int e = s0; e < s1; ++e) {
    int s = csr_src[e];
    float a = ex[(size_t)e * 4 + hh] * inv;
    acc = fmaf(a, hlin[(size_t)s * C1_ + j], acc);
  }
  float o = acc + b1[j];
  h1out[(size_t)n * C1_ + j] = o > 0.f ? o : expm1f(o);   // ELU alpha=1
}

// ---------------- GAT layer 2 (1 head, 64 ch) ----------------
__global__ __launch_bounds__(256) void k_gat2_lin(
    const float* __restrict__ h1out, const float* __restrict__ W2,
    const float* __restrict__ as2, const float* __restrict__ ad2,
    float* __restrict__ hlin2, float* __restrict__ als, float* __restrict__ ald) {
  int w = threadIdx.x >> 6, lane = threadIdx.x & 63;
  int n = blockIdx.x * 4 + w;
  __shared__ float sx[4][C1_];
  for (int k = lane; k < C1_; k += 64) sx[w][k] = h1out[(size_t)n * C1_ + k];
  __syncthreads();
  float acc = 0.f;
#pragma unroll 4
  for (int k = 0; k < C1_; ++k) acc = fmaf(sx[w][k], W2[k * HID_ + lane], acc);
  hlin2[(size_t)n * HID_ + lane] = acc;
  float vs = wave_sum(acc * as2[lane]);
  float vd = wave_sum(acc * ad2[lane]);
  if (lane == 0) { als[n] = vs; ald[n] = vd; }
}

__global__ __launch_bounds__(256) void k_gat2_attn(
    const int* __restrict__ csr_src, const int* __restrict__ indptr,
    const float* __restrict__ als, const float* __restrict__ ald,
    float* __restrict__ ex, float* __restrict__ sums) {
  int w = threadIdx.x >> 6, lane = threadIdx.x & 63;
  int n = blockIdx.x * 4 + w;
  int s0 = indptr[n], s1 = indptr[n + 1];
  float adv = ald[n];
  float mx = -1e30f, sm = 0.f;
  for (int e = s0 + lane; e < s1; e += 64) {
    float sc = als[csr_src[e]] + adv;
    sc = sc >= 0.f ? sc : 0.2f * sc;
    ex[e] = sc;
    mx = fmaxf(mx, sc);
  }
#pragma unroll
  for (int off = 32; off; off >>= 1) mx = fmaxf(mx, __shfl_xor(mx, off));
  for (int e = s0 + lane; e < s1; e += 64) {
    float v = __expf(ex[e] - mx);
    ex[e] = v;
    sm += v;
  }
  sm = wave_sum(sm);
  if (lane == 0) sums[n] = sm;
}

__global__ __launch_bounds__(256) void k_gat2_agg(
    const int* __restrict__ csr_src, const int* __restrict__ indptr,
    const float* __restrict__ ex, const float* __restrict__ sums,
    const float* __restrict__ hlin2, const float* __restrict__ b2,
    float* __restrict__ h2) {
  int w = threadIdx.x >> 6, lane = threadIdx.x & 63;
  int n = blockIdx.x * 4 + w;
  int s0 = indptr[n], s1 = indptr[n + 1];
  float inv = 1.f / (sums[n] + 1e-16f);
  float acc = 0.f;
  for (int e = s0; e < s1; ++e) {
    int s = csr_src[e];
    acc = fmaf(ex[e] * inv, hlin2[(size_t)s * HID_ + lane], acc);
  }
  h2[(size_t)n * HID_ + lane] = acc + b2[lane];
}

// ---------------- fused GRU (both layers, all T) + decoder ----------------
// grid E_/16, block 256. c = tid&127 gate-channel, rh = tid>>7 -> 8 edges each.
// State h0,h1 for 16 edges lives in LDS across all 8 timesteps; per t we gather
// h2_t[src]||h2_t[dst] (the per-t slice is ~5 MB -> cache-resident).
__device__ __forceinline__ void k4_phase(
    const float (*sx)[GH_], const float (*sh)[GH_],
    const float* __restrict__ WiT, const float* __restrict__ WhT,
    int c, int rb,
    float air[8], float aiz[8], float ain[8],
    float ahr[8], float ahz[8], float ahn[8]) {
  for (int k4 = 0; k4 < GH_ / 4; ++k4) {
    const float* wi = WiT + (size_t)k4 * 4 * G3_ + c;
    const float* wh = WhT + (size_t)k4 * 4 * G3_ + c;
    float wir0 = wi[0],   wir1 = wi[G3_],       wir2 = wi[2 * G3_],       wir3 = wi[3 * G3_];
    float wiz0 = wi[128], wiz1 = wi[G3_ + 128], wiz2 = wi[2 * G3_ + 128], wiz3 = wi[3 * G3_ + 128];
    float win0 = wi[256], win1 = wi[G3_ + 256], win2 = wi[2 * G3_ + 256], win3 = wi[3 * G3_ + 256];
    float whr0 = wh[0],   whr1 = wh[G3_],       whr2 = wh[2 * G3_],       whr3 = wh[3 * G3_];
    float whz0 = wh[128], whz1 = wh[G3_ + 128], whz2 = wh[2 * G3_ + 128], whz3 = wh[3 * G3_ + 128];
    float whn0 = wh[256], whn1 = wh[G3_ + 256], whn2 = wh[2 * G3_ + 256], whn3 = wh[3 * G3_ + 256];
#pragma unroll
    for (int r = 0; r < 8; ++r) {
      float4 xv = *(const float4*)&sx[rb + r][k4 * 4];
      float4 hv = *(const float4*)&sh[rb + r][k4 * 4];
      air[r] = fmaf(xv.x, wir0, air[r]); air[r] = fmaf(xv.y, wir1, air[r]);
      air[r] = fmaf(xv.z, wir2, air[r]); air[r] = fmaf(xv.w, wir3, air[r]);
      aiz[r] = fmaf(xv.x, wiz0, aiz[r]); aiz[r] = fmaf(xv.y, wiz1, aiz[r]);
      aiz[r] = fmaf(xv.z, wiz2, aiz[r]); aiz[r] = fmaf(xv.w, wiz3, aiz[r]);
      ain[r] = fmaf(xv.x, win0, ain[r]); ain[r] = fmaf(xv.y, win1, ain[r]);
      ain[r] = fmaf(xv.z, win2, ain[r]); ain[r] = fmaf(xv.w, win3, ain[r]);
      ahr[r] = fmaf(hv.x, whr0, ahr[r]); ahr[r] = fmaf(hv.y, whr1, ahr[r]);
      ahr[r] = fmaf(hv.z, whr2, ahr[r]); ahr[r] = fmaf(hv.w, whr3, ahr[r]);
      ahz[r] = fmaf(hv.x, whz0, ahz[r]); ahz[r] = fmaf(hv.y, whz1, ahz[r]);
      ahz[r] = fmaf(hv.z, whz2, ahz[r]); ahz[r] = fmaf(hv.w, whz3, ahz[r]);
      ahn[r] = fmaf(hv.x, whn0, ahn[r]); ahn[r] = fmaf(hv.y, whn1, ahn[r]);
      ahn[r] = fmaf(hv.z, whn2, ahn[r]); ahn[r] = fmaf(hv.w, whn3, ahn[r]);
    }
  }
}

__global__ __launch_bounds__(256) void k_gru_fused(
    const float* __restrict__ h2_all, const int* __restrict__ ei,
    const float* __restrict__ WihT0, const float* __restrict__ WhhT0,
    const float* __restrict__ WihT1, const float* __restrict__ WhhT1,
    const float* __restrict__ bih0, const float* __restrict__ bhh0,
    const float* __restrict__ bih1, const float* __restrict__ bhh1,
    const float* __restrict__ Wd1, const float* __restrict__ bd1,
    const float* __restrict__ Wd2, const float* __restrict__ bd2,
    float* __restrict__ out) {
  int tid = threadIdx.x;
  int c = tid & 127;
  int rh = tid >> 7;
  int rb = rh * 8;
  size_t i0 = (size_t)blockIdx.x * 16;
  __shared__ __align__(16) float sxy[16][GH_];   // [src64 | dst64]
  __shared__ __align__(16) float sh0[16][GH_];
  __shared__ __align__(16) float sh1[16][GH_];
  __shared__ int ssrc[16], sdst[16];
  if (tid < 16) {
    ssrc[tid] = ei[i0 + tid];
    sdst[tid] = ei[E_ + i0 + tid];
  }
  for (int r = rh; r < 16; r += 2) { sh0[r][c] = 0.f; sh1[r][c] = 0.f; }
  __syncthreads();

  float bi0r = bih0[c], bi0z = bih0[128 + c], bi0n = bih0[256 + c];
  float bh0r = bhh0[c], bh0z = bhh0[128 + c], bh0n = bhh0[256 + c];
  float bi1r = bih1[c], bi1z = bih1[128 + c], bi1n = bih1[256 + c];
  float bh1r = bhh1[c], bh1z = bhh1[128 + c], bh1n = bhh1[256 + c];

  for (int t = 0; t < T_; ++t) {
    const float* h2 = h2_all + (size_t)t * N_ * HID_;
    for (int r = rh; r < 16; r += 2) {
      int node = (c < 64) ? ssrc[r] : sdst[r];
      sxy[r][c] = h2[(size_t)node * HID_ + (c & 63)];
    }
    __syncthreads();
    // ---- layer 0: gi0 from sxy, gh0 from sh0 ----
    float air[8], aiz[8], ain[8], ahr[8], ahz[8], ahn[8];
#pragma unroll
    for (int r = 0; r < 8; ++r) {
      air[r] = bi0r; aiz[r] = bi0z; ain[r] = bi0n;
      ahr[r] = bh0r; ahz[r] = bh0z; ahn[r] = bh0n;
    }
    k4_phase(sxy, sh0, WihT0, WhhT0, c, rb, air, aiz, ain, ahr, ahz, ahn);
    float nh0[8];
#pragma unroll
    for (int r = 0; r < 8; ++r) {
      float rg = sigmoidf_(air[r] + ahr[r]);
      float zg = sigmoidf_(aiz[r] + ahz[r]);
      float ng = tanhf_(ain[r] + rg * ahn[r]);
      float hp = sh0[rb + r][c];
      nh0[r] = (1.f - zg) * ng + zg * hp;
    }
    __syncthreads();
#pragma unroll
    for (int r = 0; r < 8; ++r) sh0[rb + r][c] = nh0[r];
    __syncthreads();
    // ---- layer 1: gi1 from sh0 (new), gh1 from sh1 ----
#pragma unroll
    for (int r = 0; r < 8; ++r) {
      air[r] = bi1r; aiz[r] = bi1z; ain[r] = bi1n;
      ahr[r] = bh1r; ahz[r] = bh1z; ahn[r] = bh1n;
    }
    k4_phase(sh0, sh1, WihT1, WhhT1, c, rb, air, aiz, ain, ahr, ahz, ahn);
    float nh1[8];
#pragma unroll
    for (int r = 0; r < 8; ++r) {
      float rg = sigmoidf_(air[r] + ahr[r]);
      float zg = sigmoidf_(aiz[r] + ahz[r]);
      float ng = tanhf_(ain[r] + rg * ahn[r]);
      float hp = sh1[rb + r][c];
      nh1[r] = (1.f - zg) * ng + zg * hp;
    }
    __syncthreads();
#pragma unroll
    for (int r = 0; r < 8; ++r) sh1[rb + r][c] = nh1[r];
    __syncthreads();
  }

  // ---- decoder on final h1 (16 edges in LDS) ----
  int w = tid >> 6, lane = tid & 63;
#pragma unroll
  for (int r2 = 0; r2 < 4; ++r2) {
    int e = w * 4 + r2;
    float acc = 0.f;
#pragma unroll 8
    for (int k = 0; k < GH_; ++k) acc = fmaf(sh1[e][k], Wd1[k * 64 + lane], acc);
    float rv = fmaxf(acc + bd1[lane], 0.f);
    float contrib = wave_sum(rv * Wd2[lane]);
    if (lane == 0) out[i0 + e] = contrib + bd2[0];
  }
}

// ---------------- launch ----------------
extern "C" void kernel_launch(void* const* d_in, const int* in_sizes, int n_in,
                              void* d_out, int out_size, void* d_ws, size_t ws_size,
                              hipStream_t stream) {
  (void)in_sizes; (void)n_in; (void)out_size; (void)ws_size;
  const float* x_seq = (const float*)d_in[0];
  const int*   ei    = (const int*)d_in[1];
  const float* W1    = (const float*)d_in[2];
  const float* as1   = (const float*)d_in[3];
  const float* ad1   = (const float*)d_in[4];
  const float* b1    = (const float*)d_in[5];
  const float* W2    = (const float*)d_in[6];
  const float* as2   = (const float*)d_in[7];
  const float* ad2   = (const float*)d_in[8];
  const float* b2    = (const float*)d_in[9];
  const float* Wih0  = (const float*)d_in[10];
  const float* Whh0  = (const float*)d_in[11];
  const float* bih0  = (const float*)d_in[12];
  const float* bhh0  = (const float*)d_in[13];
  const float* Wih1  = (const float*)d_in[14];
  const float* Whh1  = (const float*)d_in[15];
  const float* bih1  = (const float*)d_in[16];
  const float* bhh1  = (const float*)d_in[17];
  const float* Wd1   = (const float*)d_in[18];
  const float* bd1   = (const float*)d_in[19];
  const float* Wd2   = (const float*)d_in[20];
  const float* bd2   = (const float*)d_in[21];
  float* out = (float*)d_out;

  char* p = (char*)d_ws;
  auto alloc = [&](size_t bytes) -> char* {
    char* r = p;
    p += (bytes + 255) & ~(size_t)255;
    return r;
  };
  // total ~97.5 MB
  float* h2_all = (float*)alloc((size_t)T_ * N_ * HID_ * 4);   // 41 MB
  float* hlin1  = (float*)alloc((size_t)N_ * C1_ * 4);         // 20.5 MB
  float* h1out  = (float*)alloc((size_t)N_ * C1_ * 4);         // 20.5 MB
  float* hlin2  = (float*)alloc((size_t)N_ * HID_ * 4);        // 5.1 MB
  float* als1   = (float*)alloc((size_t)N_ * 4 * 4);
  float* ald1   = (float*)alloc((size_t)N_ * 4 * 4);
  float* sums1  = (float*)alloc((size_t)N_ * 4 * 4);
  float* als2   = (float*)alloc((size_t)N_ * 4);
  float* ald2   = (float*)alloc((size_t)N_ * 4);
  float* sums2  = (float*)alloc((size_t)N_ * 4);
  float* ex1    = (float*)alloc((size_t)ETOT_ * 4 * 4);        // 5.4 MB
  float* ex2    = (float*)alloc((size_t)ETOT_ * 4);            // 1.4 MB
  float* WihT0  = (float*)alloc((size_t)GH_ * G3_ * 4);
  float* WhhT0  = (float*)alloc((size_t)GH_ * G3_ * 4);
  float* WihT1  = (float*)alloc((size_t)GH_ * G3_ * 4);
  float* WhhT1  = (float*)alloc((size_t)GH_ * G3_ * 4);
  int* counts   = (int*)alloc((size_t)N_ * 4);
  int* indptr   = (int*)alloc((size_t)(N_ + 1) * 4);
  int* cursors  = (int*)alloc((size_t)N_ * 4);
  int* csr      = (int*)alloc((size_t)ETOT_ * 4);              // 1.4 MB

  hipMemsetAsync(counts, 0, (size_t)N_ * 4, stream);

  k_hist<<<(ETOT_ + 255) / 256, 256, 0, stream>>>(ei, counts);
  k_scan<<<1, 1024, 0, stream>>>(counts, indptr);
  k_copy<<<(N_ + 255) / 256, 256, 0, stream>>>(indptr, cursors);
  k_scatter<<<(ETOT_ + 255) / 256, 256, 0, stream>>>(ei, cursors, csr);
  k_transpose<<<(G3_ * GH_ + 255) / 256, 256, 0, stream>>>(Wih0, WihT0);
  k_transpose<<<(G3_ * GH_ + 255) / 256, 256, 0, stream>>>(Whh0, WhhT0);
  k_transpose<<<(G3_ * GH_ + 255) / 256, 256, 0, stream>>>(Wih1, WihT1);
  k_transpose<<<(G3_ * GH_ + 255) / 256, 256, 0, stream>>>(Whh1, WhhT1);

  for (int t = 0; t < T_; ++t) {
    const float* xt = x_seq + (size_t)t * N_ * FIN_;
    float* h2t = h2_all + (size_t)t * N_ * HID_;
    k_gat1_lin<<<N_, 256, 0, stream>>>(xt, W1, as1, ad1, hlin1, als1, ald1);
    k_gat1_attn<<<N_ / 4, 256, 0, stream>>>(csr, indptr, als1, ald1, ex1, sums1);
    k_gat1_agg<<<N_, 256, 0, stream>>>(csr, indptr, ex1, sums1, hlin1, b1, h1out);
    k_gat2_lin<<<N_ / 4, 256, 0, stream>>>(h1out, W2, as2, ad2, hlin2, als2, ald2);
    k_gat2_attn<<<N_ / 4, 256, 0, stream>>>(csr, indptr, als2, ald2, ex2, sums2);
    k_gat2_agg<<<N_ / 4, 256, 0, stream>>>(csr, indptr, ex2, sums2, hlin2, b2, h2t);
  }
  k_gru_fused<<<E_ / 16, 256, 0, stream>>>(
      h2_all, ei, WihT0, WhhT0, WihT1, WhhT1,
      bih0, bhh0, bih1, bhh1, Wd1, bd1, Wd2, bd2, out);
}

// Round 3
// 9931.490 us; speedup vs baseline: 1.7532x; 1.7532x over previous
//
#include <hip/hip_runtime.h>
#include <math.h>

#define T_ 8
#define N_ 20000
#define E_ 320000
#define ETOT_ (E_ + N_)
#define FIN_ 32
#define C1_ 256   // HEADS*HID
#define HID_ 64
#define G3_ 384   // 3*GH
#define GH_ 128
#define MB_ 64    // edges per block in fused GRU
#define LDP_ 136  // padded inner dim (bf16 elems) for LDS state arrays
#define NPACK_ (24 * 4 * 64 * 8)   // packed weight elems per matrix

typedef __attribute__((ext_vector_type(8))) short s8v;
typedef __attribute__((ext_vector_type(4))) float f4v;

// ---------------- helpers ----------------
__device__ __forceinline__ float wave_sum(float v) {
#pragma unroll
  for (int off = 32; off; off >>= 1) v += __shfl_down(v, off);
  return v;
}
__device__ __forceinline__ float sigmoidf_(float x) { return 1.f / (1.f + __expf(-x)); }
__device__ __forceinline__ float tanhf_(float x) {
  float e2 = __expf(2.f * x);
  return 1.f - 2.f / (e2 + 1.f);
}
__device__ __forceinline__ unsigned short f2bf(float f) {
  union { float f; unsigned int u; } v; v.f = f;
  unsigned int r = v.u + 0x7FFFu + ((v.u >> 16) & 1u);   // RNE
  return (unsigned short)(r >> 16);
}
__device__ __forceinline__ float bf2f(unsigned short h) {
  union { unsigned int u; float f; } v; v.u = ((unsigned int)h) << 16;
  return v.f;
}
__device__ __forceinline__ void edge_sd(const int* ei, int e, int& s, int& d) {
  if (e < E_) { s = ei[e]; d = ei[E_ + e]; }
  else { s = e - E_; d = e - E_; }
}

// ---------------- CSR build (by dst) ----------------
__global__ void k_hist(const int* __restrict__ ei, int* __restrict__ counts) {
  int e = blockIdx.x * 256 + threadIdx.x;
  if (e >= ETOT_) return;
  int s, d; edge_sd(ei, e, s, d);
  atomicAdd(&counts[d], 1);
}

__global__ void k_scan(const int* __restrict__ counts, int* __restrict__ indptr) {
  __shared__ int tmp[1024];
  __shared__ int carry;
  int tid = threadIdx.x;
  if (tid == 0) { carry = 0; indptr[0] = 0; }
  __syncthreads();
  for (int base = 0; base < N_; base += 1024) {
    int i = base + tid;
    int v = (i < N_) ? counts[i] : 0;
    tmp[tid] = v;
    __syncthreads();
    for (int off = 1; off < 1024; off <<= 1) {
      int add = (tid >= off) ? tmp[tid - off] : 0;
      __syncthreads();
      tmp[tid] += add;
      __syncthreads();
    }
    if (i < N_) indptr[i + 1] = carry + tmp[tid];
    __syncthreads();
    if (tid == 1023) carry += tmp[1023];
    __syncthreads();
  }
}

__global__ void k_copy(const int* __restrict__ indptr, int* __restrict__ cursors) {
  int i = blockIdx.x * 256 + threadIdx.x;
  if (i < N_) cursors[i] = indptr[i];
}

__global__ void k_scatter(const int* __restrict__ ei, int* __restrict__ cursors,
                          int* __restrict__ csr_src) {
  int e = blockIdx.x * 256 + threadIdx.x;
  if (e >= ETOT_) return;
  int s, d; edge_sd(ei, e, s, d);
  int pos = atomicAdd(&cursors[d], 1);
  csr_src[pos] = s;
}

// ---------------- weight pack: W[384][128] fp32 -> B-fragment-ordered bf16 hi/lo ----
// flat idx = ((nt*4 + ks)*64 + lane)*8 + j ;  value = W[nt*16 + (lane&15)][ks*32 + (lane>>4)*8 + j]
__global__ void k_packW(const float* __restrict__ W, unsigned short* __restrict__ Bh,
                        unsigned short* __restrict__ Bl) {
  int idx = blockIdx.x * 256 + threadIdx.x;
  if (idx >= NPACK_) return;
  int j = idx & 7, lane = (idx >> 3) & 63, ks = (idx >> 9) & 3, nt = idx >> 11;
  int n = nt * 16 + (lane & 15);
  int k = ks * 32 + (lane >> 4) * 8 + j;
  float v = W[n * GH_ + k];
  unsigned short h = f2bf(v);
  Bh[idx] = h;
  Bl[idx] = f2bf(v - bf2f(h));
}

// ---------------- GAT layer 1 ----------------
__global__ __launch_bounds__(256) void k_gat1_lin(
    const float* __restrict__ x, const float* __restrict__ W1,
    const float* __restrict__ as1, const float* __restrict__ ad1,
    float* __restrict__ hlin, float* __restrict__ als, float* __restrict__ ald) {
  int n = blockIdx.x;
  int j = threadIdx.x;
  __shared__ float sx[FIN_];
  if (j < FIN_) sx[j] = x[n * FIN_ + j];
  __syncthreads();
  float acc = 0.f;
#pragma unroll
  for (int k = 0; k < FIN_; ++k) acc = fmaf(sx[k], W1[k * C1_ + j], acc);
  hlin[(size_t)n * C1_ + j] = acc;
  int h = j >> 6, c = j & 63;
  float vs = wave_sum(acc * as1[h * 64 + c]);
  float vd = wave_sum(acc * ad1[h * 64 + c]);
  if (c == 0) { als[n * 4 + h] = vs; ald[n * 4 + h] = vd; }
}

__global__ __launch_bounds__(256) void k_gat1_attn(
    const int* __restrict__ csr_src, const int* __restrict__ indptr,
    const float* __restrict__ als, const float* __restrict__ ald,
    float* __restrict__ ex, float* __restrict__ sums) {
  int w = threadIdx.x >> 6, lane = threadIdx.x & 63;
  int n = blockIdx.x * 4 + w;
  int s0 = indptr[n], s1 = indptr[n + 1];
  float adv[4], mx[4], sm[4];
#pragma unroll
  for (int h = 0; h < 4; ++h) { adv[h] = ald[n * 4 + h]; mx[h] = -1e30f; sm[h] = 0.f; }
  for (int e = s0 + lane; e < s1; e += 64) {
    int s = csr_src[e];
#pragma unroll
    for (int h = 0; h < 4; ++h) {
      float sc = als[s * 4 + h] + adv[h];
      sc = sc >= 0.f ? sc : 0.2f * sc;
      ex[(size_t)e * 4 + h] = sc;
      mx[h] = fmaxf(mx[h], sc);
    }
  }
#pragma unroll
  for (int h = 0; h < 4; ++h) {
#pragma unroll
    for (int off = 32; off; off >>= 1) mx[h] = fmaxf(mx[h], __shfl_xor(mx[h], off));
  }
  for (int e = s0 + lane; e < s1; e += 64) {
#pragma unroll
    for (int h = 0; h < 4; ++h) {
      float v = __expf(ex[(size_t)e * 4 + h] - mx[h]);
      ex[(size_t)e * 4 + h] = v;
      sm[h] += v;
    }
  }
#pragma unroll
  for (int h = 0; h < 4; ++h) sm[h] = wave_sum(sm[h]);
  if (lane == 0) {
#pragma unroll
    for (int h = 0; h < 4; ++h) sums[n * 4 + h] = sm[h];
  }
}

__global__ __launch_bounds__(256) void k_gat1_agg(
    const int* __restrict__ csr_src, const int* __restrict__ indptr,
    const float* __restrict__ ex, const float* __restrict__ sums,
    const float* __restrict__ hlin, const float* __restrict__ b1,
    float* __restrict__ h1out) {
  int n = blockIdx.x;
  int j = threadIdx.x;
  int hh = j >> 6;
  int s0 = indptr[n], s1 = indptr[n + 1];
  float inv = 1.f / (sums[n * 4 + hh] + 1e-16f);
  float acc = 0.f;
  for (int e = s0; e < s1; ++e) {
    int s = csr_src[e];
    float a = ex[(size_t)e * 4 + hh] * inv;
    acc = fmaf(a, hlin[(size_t)s * C1_ + j], acc);
  }
  float o = acc + b1[j];
  h1out[(size_t)n * C1_ + j] = o > 0.f ? o : expm1f(o);
}

// ---------------- GAT layer 2 ----------------
__global__ __launch_bounds__(256) void k_gat2_lin(
    const float* __restrict__ h1out, const float* __restrict__ W2,
    const float* __restrict__ as2, const float* __restrict__ ad2,
    float* __restrict__ hlin2, float* __restrict__ als, float* __restrict__ ald) {
  int w = threadIdx.x >> 6, lane = threadIdx.x & 63;
  int n = blockIdx.x * 4 + w;
  __shared__ float sx[4][C1_];
  for (int k = lane; k < C1_; k += 64) sx[w][k] = h1out[(size_t)n * C1_ + k];
  __syncthreads();
  float acc = 0.f;
#pragma unroll 4
  for (int k = 0; k < C1_; ++k) acc = fmaf(sx[w][k], W2[k * HID_ + lane], acc);
  hlin2[(size_t)n * HID_ + lane] = acc;
  float vs = wave_sum(acc * as2[lane]);
  float vd = wave_sum(acc * ad2[lane]);
  if (lane == 0) { als[n] = vs; ald[n] = vd; }
}

__global__ __launch_bounds__(256) void k_gat2_attn(
    const int* __restrict__ csr_src, const int* __restrict__ indptr,
    const float* __restrict__ als, const float* __restrict__ ald,
    float* __restrict__ ex, float* __restrict__ sums) {
  int w = threadIdx.x >> 6, lane = threadIdx.x & 63;
  int n = blockIdx.x * 4 + w;
  int s0 = indptr[n], s1 = indptr[n + 1];
  float adv = ald[n];
  float mx = -1e30f, sm = 0.f;
  for (int e = s0 + lane; e < s1; e += 64) {
    float sc = als[csr_src[e]] + adv;
    sc = sc >= 0.f ? sc : 0.2f * sc;
    ex[e] = sc;
    mx = fmaxf(mx, sc);
  }
#pragma unroll
  for (int off = 32; off; off >>= 1) mx = fmaxf(mx, __shfl_xor(mx, off));
  for (int e = s0 + lane; e < s1; e += 64) {
    float v = __expf(ex[e] - mx);
    ex[e] = v;
    sm += v;
  }
  sm = wave_sum(sm);
  if (lane == 0) sums[n] = sm;
}

__global__ __launch_bounds__(256) void k_gat2_agg(
    const int* __restrict__ csr_src, const int* __restrict__ indptr,
    const float* __restrict__ ex, const float* __restrict__ sums,
    const float* __restrict__ hlin2, const float* __restrict__ b2,
    float* __restrict__ h2) {
  int w = threadIdx.x >> 6, lane = threadIdx.x & 63;
  int n = blockIdx.x * 4 + w;
  int s0 = indptr[n], s1 = indptr[n + 1];
  float inv = 1.f / (sums[n] + 1e-16f);
  float acc = 0.f;
  for (int e = s0; e < s1; ++e) {
    int s = csr_src[e];
    acc = fmaf(ex[e] * inv, hlin2[(size_t)s * HID_ + lane], acc);
  }
  h2[(size_t)n * HID_ + lane] = acc + b2[lane];
}

// ---------------- MFMA GRU ----------------
// bf16x3: C += Ah*Bh + Al*Bh + Ah*Bl   (Al*Bl dropped, ~2^-18 rel)
__device__ __forceinline__ void mfma3(f4v& acc, s8v ah, s8v al, s8v bh, s8v bl) {
  acc = __builtin_amdgcn_mfma_f32_16x16x32_bf16(ah, bh, acc, 0, 0, 0);
  acc = __builtin_amdgcn_mfma_f32_16x16x32_bf16(al, bh, acc, 0, 0, 0);
  acc = __builtin_amdgcn_mfma_f32_16x16x32_bf16(ah, bl, acc, 0, 0, 0);
}

// One matvec pass: C[64 edges][my 96 gate cols] += A[64][128] * W[128][384-subset]
// A in LDS as bf16 hi/lo [64][LDP_]; B packed in global fragment order.
// Wave w owns N-tiles: r {2w,2w+1}, z {8+2w,8+2w+1}, n {16+2w,16+2w+1}.
__device__ __forceinline__ void mfma_pass(
    const unsigned short* Ah_, const unsigned short* Al_,
    const unsigned short* __restrict__ Bh_, const unsigned short* __restrict__ Bl_,
    int w, int lane, f4v Cr[2][4], f4v Cz[2][4], f4v Cn[2][4]) {
  const int mrow = lane & 15, quad = lane >> 4;
#pragma unroll
  for (int ks = 0; ks < 4; ++ks) {
    s8v Ah[4], Al[4];
    const int aoff = mrow * LDP_ + ks * 32 + quad * 8;
#pragma unroll
    for (int mt = 0; mt < 4; ++mt) {
      Ah[mt] = *(const s8v*)(Ah_ + aoff + mt * (16 * LDP_));
      Al[mt] = *(const s8v*)(Al_ + aoff + mt * (16 * LDP_));
    }
#pragma unroll
    for (int jt = 0; jt < 2; ++jt) {
      const int ntr = 2 * w + jt, ntz = 8 + 2 * w + jt, ntn = 16 + 2 * w + jt;
      const s8v brh = *(const s8v*)(Bh_ + ((size_t)(ntr * 4 + ks) * 64 + lane) * 8);
      const s8v brl = *(const s8v*)(Bl_ + ((size_t)(ntr * 4 + ks) * 64 + lane) * 8);
      const s8v bzh = *(const s8v*)(Bh_ + ((size_t)(ntz * 4 + ks) * 64 + lane) * 8);
      const s8v bzl = *(const s8v*)(Bl_ + ((size_t)(ntz * 4 + ks) * 64 + lane) * 8);
      const s8v bnh = *(const s8v*)(Bh_ + ((size_t)(ntn * 4 + ks) * 64 + lane) * 8);
      const s8v bnl = *(const s8v*)(Bl_ + ((size_t)(ntn * 4 + ks) * 64 + lane) * 8);
#pragma unroll
      for (int mt = 0; mt < 4; ++mt) {
        mfma3(Cr[jt][mt], Ah[mt], Al[mt], brh, brl);
        mfma3(Cz[jt][mt], Ah[mt], Al[mt], bzh, bzl);
        mfma3(Cn[jt][mt], Ah[mt], Al[mt], bnh, bnl);
      }
    }
  }
}

__global__ __launch_bounds__(256, 1) void k_gru_mfma(
    const float* __restrict__ h2_all, const int* __restrict__ ei,
    const unsigned short* __restrict__ pWih0h, const unsigned short* __restrict__ pWih0l,
    const unsigned short* __restrict__ pWhh0h, const unsigned short* __restrict__ pWhh0l,
    const unsigned short* __restrict__ pWih1h, const unsigned short* __restrict__ pWih1l,
    const unsigned short* __restrict__ pWhh1h, const unsigned short* __restrict__ pWhh1l,
    const float* __restrict__ bih0, const float* __restrict__ bhh0,
    const float* __restrict__ bih1, const float* __restrict__ bhh1,
    const float* __restrict__ Wd1, const float* __restrict__ bd1,
    const float* __restrict__ Wd2, const float* __restrict__ bd2,
    float* __restrict__ out) {
  __shared__ unsigned short sxh[MB_ * LDP_], sxl[MB_ * LDP_];
  __shared__ unsigned short h0h[MB_ * LDP_], h0l[MB_ * LDP_];
  __shared__ unsigned short h1h[MB_ * LDP_], h1l[MB_ * LDP_];
  __shared__ int ssrc[MB_], sdst[MB_];
  const int tid = threadIdx.x;
  const int lane = tid & 63, w = tid >> 6;
  const int col = lane & 15, quad = lane >> 4;
  const size_t i0 = (size_t)blockIdx.x * MB_;

  if (tid < MB_) { ssrc[tid] = ei[i0 + tid]; sdst[tid] = ei[E_ + i0 + tid]; }
  for (int idx = tid; idx < MB_ * LDP_; idx += 256) {
    h0h[idx] = 0; h0l[idx] = 0; h1h[idx] = 0; h1l[idx] = 0;
  }
  // per-lane biases for owned gate cols
  float br0[2], bz0[2], bin0[2], bhn0[2], br1[2], bz1[2], bin1[2], bhn1[2];
#pragma unroll
  for (int jt = 0; jt < 2; ++jt) {
    int cg = 32 * w + jt * 16 + col;
    br0[jt] = bih0[cg] + bhh0[cg];
    bz0[jt] = bih0[128 + cg] + bhh0[128 + cg];
    bin0[jt] = bih0[256 + cg]; bhn0[jt] = bhh0[256 + cg];
    br1[jt] = bih1[cg] + bhh1[cg];
    bz1[jt] = bih1[128 + cg] + bhh1[128 + cg];
    bin1[jt] = bih1[256 + cg]; bhn1[jt] = bhh1[256 + cg];
  }
  __syncthreads();

  const int c4 = (tid & 31) * 4;   // gather: channel group
  const int rr = tid >> 5;         // gather: edge row phase

  for (int t = 0; t < T_; ++t) {
    const float* h2 = h2_all + (size_t)t * (N_ * HID_);
    // ---- gather X = [h2[src] | h2[dst]] -> bf16 hi/lo in LDS ----
#pragma unroll
    for (int p = 0; p < 8; ++p) {
      int e = rr + p * 8;
      int node = (c4 < 64) ? ssrc[e] : sdst[e];
      float4 v = *(const float4*)(h2 + (size_t)node * HID_ + (c4 & 63));
      ushort4 hh, ll;
      hh.x = f2bf(v.x); ll.x = f2bf(v.x - bf2f(hh.x));
      hh.y = f2bf(v.y); ll.y = f2bf(v.y - bf2f(hh.y));
      hh.z = f2bf(v.z); ll.z = f2bf(v.z - bf2f(hh.z));
      hh.w = f2bf(v.w); ll.w = f2bf(v.w - bf2f(hh.w));
      *(ushort4*)&sxh[e * LDP_ + c4] = hh;
      *(ushort4*)&sxl[e * LDP_ + c4] = ll;
    }
    __syncthreads();

    f4v Cr[2][4], Cz[2][4], Cin[2][4], Chn[2][4];
    // ---- layer 0 ----
#pragma unroll
    for (int jt = 0; jt < 2; ++jt)
#pragma unroll
      for (int mt = 0; mt < 4; ++mt) {
        Cr[jt][mt] = (f4v){br0[jt], br0[jt], br0[jt], br0[jt]};
        Cz[jt][mt] = (f4v){bz0[jt], bz0[jt], bz0[jt], bz0[jt]};
        Cin[jt][mt] = (f4v){bin0[jt], bin0[jt], bin0[jt], bin0[jt]};
        Chn[jt][mt] = (f4v){bhn0[jt], bhn0[jt], bhn0[jt], bhn0[jt]};
      }
    mfma_pass(sxh, sxl, pWih0h, pWih0l, w, lane, Cr, Cz, Cin);
    mfma_pass(h0h, h0l, pWhh0h, pWhh0l, w, lane, Cr, Cz, Chn);
    __syncthreads();   // all waves done reading h0
#pragma unroll
    for (int jt = 0; jt < 2; ++jt)
#pragma unroll
      for (int mt = 0; mt < 4; ++mt)
#pragma unroll
        for (int reg = 0; reg < 4; ++reg) {
          int e = mt * 16 + quad * 4 + reg;
          int ch = 32 * w + jt * 16 + col;
          float r = sigmoidf_(Cr[jt][mt][reg]);
          float z = sigmoidf_(Cz[jt][mt][reg]);
          float n = tanhf_(Cin[jt][mt][reg] + r * Chn[jt][mt][reg]);
          float hp = bf2f(h0h[e * LDP_ + ch]) + bf2f(h0l[e * LDP_ + ch]);
          float hv = (1.f - z) * n + z * hp;
          unsigned short hb = f2bf(hv);
          h0h[e * LDP_ + ch] = hb;
          h0l[e * LDP_ + ch] = f2bf(hv - bf2f(hb));
        }
    __syncthreads();
    // ---- layer 1 ----
#pragma unroll
    for (int jt = 0; jt < 2; ++jt)
#pragma unroll
      for (int mt = 0; mt < 4; ++mt) {
        Cr[jt][mt] = (f4v){br1[jt], br1[jt], br1[jt], br1[jt]};
        Cz[jt][mt] = (f4v){bz1[jt], bz1[jt], bz1[jt], bz1[jt]};
        Cin[jt][mt] = (f4v){bin1[jt], bin1[jt], bin1[jt], bin1[jt]};
        Chn[jt][mt] = (f4v){bhn1[jt], bhn1[jt], bhn1[jt], bhn1[jt]};
      }
    mfma_pass(h0h, h0l, pWih1h, pWih1l, w, lane, Cr, Cz, Cin);
    mfma_pass(h1h, h1l, pWhh1h, pWhh1l, w, lane, Cr, Cz, Chn);
    __syncthreads();
#pragma unroll
    for (int jt = 0; jt < 2; ++jt)
#pragma unroll
      for (int mt = 0; mt < 4; ++mt)
#pragma unroll
        for (int reg = 0; reg < 4; ++reg) {
          int e = mt * 16 + quad * 4 + reg;
          int ch = 32 * w + jt * 16 + col;
          float r = sigmoidf_(Cr[jt][mt][reg]);
          float z = sigmoidf_(Cz[jt][mt][reg]);
          float n = tanhf_(Cin[jt][mt][reg] + r * Chn[jt][mt][reg]);
          float hp = bf2f(h1h[e * LDP_ + ch]) + bf2f(h1l[e * LDP_ + ch]);
          float hv = (1.f - z) * n + z * hp;
          unsigned short hb = f2bf(hv);
          h1h[e * LDP_ + ch] = hb;
          h1l[e * LDP_ + ch] = f2bf(hv - bf2f(hb));
        }
    __syncthreads();
  }

  // ---- decoder: out = relu(h1 @ Wd1 + bd1) @ Wd2 + bd2 ----
  for (int ee = 0; ee < 16; ++ee) {
    int e = w * 16 + ee;
    float acc = 0.f;
#pragma unroll 8
    for (int k = 0; k < GH_; ++k) {
      float hvv = bf2f(h1h[e * LDP_ + k]) + bf2f(h1l[e * LDP_ + k]);
      acc = fmaf(hvv, Wd1[k * 64 + lane], acc);
    }
    float rv = fmaxf(acc + bd1[lane], 0.f);
    float contrib = wave_sum(rv * Wd2[lane]);
    if (lane == 0) out[i0 + e] = contrib + bd2[0];
  }
}

// ---------------- launch ----------------
extern "C" void kernel_launch(void* const* d_in, const int* in_sizes, int n_in,
                              void* d_out, int out_size, void* d_ws, size_t ws_size,
                              hipStream_t stream) {
  (void)in_sizes; (void)n_in; (void)out_size; (void)ws_size;
  const float* x_seq = (const float*)d_in[0];
  const int*   ei    = (const int*)d_in[1];
  const float* W1    = (const float*)d_in[2];
  const float* as1   = (const float*)d_in[3];
  const float* ad1   = (const float*)d_in[4];
  const float* b1    = (const float*)d_in[5];
  const float* W2    = (const float*)d_in[6];
  const float* as2   = (const float*)d_in[7];
  const float* ad2   = (const float*)d_in[8];
  const float* b2    = (const float*)d_in[9];
  const float* Wih0  = (const float*)d_in[10];
  const float* Whh0  = (const float*)d_in[11];
  const float* bih0  = (const float*)d_in[12];
  const float* bhh0  = (const float*)d_in[13];
  const float* Wih1  = (const float*)d_in[14];
  const float* Whh1  = (const float*)d_in[15];
  const float* bih1  = (const float*)d_in[16];
  const float* bhh1  = (const float*)d_in[17];
  const float* Wd1   = (const float*)d_in[18];
  const float* bd1   = (const float*)d_in[19];
  const float* Wd2   = (const float*)d_in[20];
  const float* bd2   = (const float*)d_in[21];
  float* out = (float*)d_out;

  char* p = (char*)d_ws;
  auto alloc = [&](size_t bytes) -> char* {
    char* r = p;
    p += (bytes + 255) & ~(size_t)255;
    return r;
  };
  float* h2_all = (float*)alloc((size_t)T_ * N_ * HID_ * 4);   // 41 MB
  float* hlin1  = (float*)alloc((size_t)N_ * C1_ * 4);
  float* h1out  = (float*)alloc((size_t)N_ * C1_ * 4);
  float* hlin2  = (float*)alloc((size_t)N_ * HID_ * 4);
  float* als1   = (float*)alloc((size_t)N_ * 4 * 4);
  float* ald1   = (float*)alloc((size_t)N_ * 4 * 4);
  float* sums1  = (float*)alloc((size_t)N_ * 4 * 4);
  float* als2   = (float*)alloc((size_t)N_ * 4);
  float* ald2   = (float*)alloc((size_t)N_ * 4);
  float* sums2  = (float*)alloc((size_t)N_ * 4);
  float* ex1    = (float*)alloc((size_t)ETOT_ * 4 * 4);
  float* ex2    = (float*)alloc((size_t)ETOT_ * 4);
  unsigned short* pWih0h = (unsigned short*)alloc(NPACK_ * 2);
  unsigned short* pWih0l = (unsigned short*)alloc(NPACK_ * 2);
  unsigned short* pWhh0h = (unsigned short*)alloc(NPACK_ * 2);
  unsigned short* pWhh0l = (unsigned short*)alloc(NPACK_ * 2);
  unsigned short* pWih1h = (unsigned short*)alloc(NPACK_ * 2);
  unsigned short* pWih1l = (unsigned short*)alloc(NPACK_ * 2);
  unsigned short* pWhh1h = (unsigned short*)alloc(NPACK_ * 2);
  unsigned short* pWhh1l = (unsigned short*)alloc(NPACK_ * 2);
  int* counts   = (int*)alloc((size_t)N_ * 4);
  int* indptr   = (int*)alloc((size_t)(N_ + 1) * 4);
  int* cursors  = (int*)alloc((size_t)N_ * 4);
  int* csr      = (int*)alloc((size_t)ETOT_ * 4);

  hipMemsetAsync(counts, 0, (size_t)N_ * 4, stream);

  k_hist<<<(ETOT_ + 255) / 256, 256, 0, stream>>>(ei, counts);
  k_scan<<<1, 1024, 0, stream>>>(counts, indptr);
  k_copy<<<(N_ + 255) / 256, 256, 0, stream>>>(indptr, cursors);
  k_scatter<<<(ETOT_ + 255) / 256, 256, 0, stream>>>(ei, cursors, csr);
  const int pb = (NPACK_ + 255) / 256;
  k_packW<<<pb, 256, 0, stream>>>(Wih0, pWih0h, pWih0l);
  k_packW<<<pb, 256, 0, stream>>>(Whh0, pWhh0h, pWhh0l);
  k_packW<<<pb, 256, 0, stream>>>(Wih1, pWih1h, pWih1l);
  k_packW<<<pb, 256, 0, stream>>>(Whh1, pWhh1h, pWhh1l);

  for (int t = 0; t < T_; ++t) {
    const float* xt = x_seq + (size_t)t * N_ * FIN_;
    float* h2t = h2_all + (size_t)t * N_ * HID_;
    k_gat1_lin<<<N_, 256, 0, stream>>>(xt, W1, as1, ad1, hlin1, als1, ald1);
    k_gat1_attn<<<N_ / 4, 256, 0, stream>>>(csr, indptr, als1, ald1, ex1, sums1);
    k_gat1_agg<<<N_, 256, 0, stream>>>(csr, indptr, ex1, sums1, hlin1, b1, h1out);
    k_gat2_lin<<<N_ / 4, 256, 0, stream>>>(h1out, W2, as2, ad2, hlin2, als2, ald2);
    k_gat2_attn<<<N_ / 4, 256, 0, stream>>>(csr, indptr, als2, ald2, ex2, sums2);
    k_gat2_agg<<<N_ / 4, 256, 0, stream>>>(csr, indptr, ex2, sums2, hlin2, b2, h2t);
  }
  k_gru_mfma<<<E_ / MB_, 256, 0, stream>>>(
      h2_all, ei,
      pWih0h, pWih0l, pWhh0h, pWhh0l, pWih1h, pWih1l, pWhh1h, pWhh1l,
      bih0, bhh0, bih1, bhh1, Wd1, bd1, Wd2, bd2, out);
}

// Round 5
// 9368.851 us; speedup vs baseline: 1.8585x; 1.0601x over previous
//
#include <hip/hip_runtime.h>
#include <math.h>

#define T_ 8
#define N_ 20000
#define E_ 320000
#define ETOT_ (E_ + N_)
#define FIN_ 32
#define C1_ 256   // HEADS*HID
#define HID_ 64
#define G3_ 384   // 3*GH
#define GH_ 128
#define MB_ 64    // edges per block in fused GRU
#define LDP_ 136  // padded inner dim (bf16 elems) for LDS state arrays
#define NPACK_ (24 * 4 * 64 * 8)   // packed weight elems per matrix

typedef __attribute__((ext_vector_type(8))) short s8v;
typedef __attribute__((ext_vector_type(4))) float f4v;   // native vector (MFMA acc + nt loads)

// ---------------- helpers ----------------
__device__ __forceinline__ float wave_sum(float v) {
#pragma unroll
  for (int off = 32; off; off >>= 1) v += __shfl_down(v, off);
  return v;
}
__device__ __forceinline__ float sigmoidf_(float x) { return 1.f / (1.f + __expf(-x)); }
__device__ __forceinline__ float tanhf_(float x) {
  float e2 = __expf(2.f * x);
  return 1.f - 2.f / (e2 + 1.f);
}
__device__ __forceinline__ unsigned short f2bf(float f) {
  union { float f; unsigned int u; } v; v.f = f;
  unsigned int r = v.u + 0x7FFFu + ((v.u >> 16) & 1u);   // RNE
  return (unsigned short)(r >> 16);
}
__device__ __forceinline__ float bf2f(unsigned short h) {
  union { unsigned int u; float f; } v; v.u = ((unsigned int)h) << 16;
  return v.f;
}
__device__ __forceinline__ void edge_sd(const int* ei, int e, int& s, int& d) {
  if (e < E_) { s = ei[e]; d = ei[E_ + e]; }
  else { s = e - E_; d = e - E_; }
}

// ---------------- CSR build (by dst) ----------------
__global__ void k_hist(const int* __restrict__ ei, int* __restrict__ counts) {
  int e = blockIdx.x * 256 + threadIdx.x;
  if (e >= ETOT_) return;
  int s, d; edge_sd(ei, e, s, d);
  atomicAdd(&counts[d], 1);
}

__global__ void k_scan(const int* __restrict__ counts, int* __restrict__ indptr) {
  __shared__ int tmp[1024];
  __shared__ int carry;
  int tid = threadIdx.x;
  if (tid == 0) { carry = 0; indptr[0] = 0; }
  __syncthreads();
  for (int base = 0; base < N_; base += 1024) {
    int i = base + tid;
    int v = (i < N_) ? counts[i] : 0;
    tmp[tid] = v;
    __syncthreads();
    for (int off = 1; off < 1024; off <<= 1) {
      int add = (tid >= off) ? tmp[tid - off] : 0;
      __syncthreads();
      tmp[tid] += add;
      __syncthreads();
    }
    if (i < N_) indptr[i + 1] = carry + tmp[tid];
    __syncthreads();
    if (tid == 1023) carry += tmp[1023];
    __syncthreads();
  }
}

__global__ void k_copy(const int* __restrict__ indptr, int* __restrict__ cursors) {
  int i = blockIdx.x * 256 + threadIdx.x;
  if (i < N_) cursors[i] = indptr[i];
}

__global__ void k_scatter(const int* __restrict__ ei, int* __restrict__ cursors,
                          int* __restrict__ csr_src) {
  int e = blockIdx.x * 256 + threadIdx.x;
  if (e >= ETOT_) return;
  int s, d; edge_sd(ei, e, s, d);
  int pos = atomicAdd(&cursors[d], 1);
  csr_src[pos] = s;
}

// ---------------- weight pack: W[384][128] fp32 -> B-fragment-ordered bf16 hi/lo ----
// flat idx = ((nt*4 + ks)*64 + lane)*8 + j ;  value = W[nt*16 + (lane&15)][ks*32 + (lane>>4)*8 + j]
__global__ void k_packW(const float* __restrict__ W, unsigned short* __restrict__ Bh,
                        unsigned short* __restrict__ Bl) {
  int idx = blockIdx.x * 256 + threadIdx.x;
  if (idx >= NPACK_) return;
  int j = idx & 7, lane = (idx >> 3) & 63, ks = (idx >> 9) & 3, nt = idx >> 11;
  int n = nt * 16 + (lane & 15);
  int k = ks * 32 + (lane >> 4) * 8 + j;
  float v = W[n * GH_ + k];
  unsigned short h = f2bf(v);
  Bh[idx] = h;
  Bl[idx] = f2bf(v - bf2f(h));
}

// ---------------- GAT layer 1 ----------------
__global__ __launch_bounds__(256) void k_gat1_lin(
    const float* __restrict__ x, const float* __restrict__ W1,
    const float* __restrict__ as1, const float* __restrict__ ad1,
    float* __restrict__ hlin, float* __restrict__ als, float* __restrict__ ald) {
  int n = blockIdx.x;
  int j = threadIdx.x;
  __shared__ float sx[FIN_];
  if (j < FIN_) sx[j] = x[n * FIN_ + j];
  __syncthreads();
  float acc = 0.f;
#pragma unroll
  for (int k = 0; k < FIN_; ++k) acc = fmaf(sx[k], W1[k * C1_ + j], acc);
  hlin[(size_t)n * C1_ + j] = acc;
  int h = j >> 6, c = j & 63;
  float vs = wave_sum(acc * as1[h * 64 + c]);
  float vd = wave_sum(acc * ad1[h * 64 + c]);
  if (c == 0) { als[n * 4 + h] = vs; ald[n * 4 + h] = vd; }
}

__global__ __launch_bounds__(256) void k_gat1_attn(
    const int* __restrict__ csr_src, const int* __restrict__ indptr,
    const float* __restrict__ als, const float* __restrict__ ald,
    float* __restrict__ ex, float* __restrict__ sums) {
  int w = threadIdx.x >> 6, lane = threadIdx.x & 63;
  int n = blockIdx.x * 4 + w;
  int s0 = indptr[n], s1 = indptr[n + 1];
  float adv[4], mx[4], sm[4];
#pragma unroll
  for (int h = 0; h < 4; ++h) { adv[h] = ald[n * 4 + h]; mx[h] = -1e30f; sm[h] = 0.f; }
  for (int e = s0 + lane; e < s1; e += 64) {
    int s = csr_src[e];
#pragma unroll
    for (int h = 0; h < 4; ++h) {
      float sc = als[s * 4 + h] + adv[h];
      sc = sc >= 0.f ? sc : 0.2f * sc;
      ex[(size_t)e * 4 + h] = sc;
      mx[h] = fmaxf(mx[h], sc);
    }
  }
#pragma unroll
  for (int h = 0; h < 4; ++h) {
#pragma unroll
    for (int off = 32; off; off >>= 1) mx[h] = fmaxf(mx[h], __shfl_xor(mx[h], off));
  }
  for (int e = s0 + lane; e < s1; e += 64) {
#pragma unroll
    for (int h = 0; h < 4; ++h) {
      float v = __expf(ex[(size_t)e * 4 + h] - mx[h]);
      ex[(size_t)e * 4 + h] = v;
      sm[h] += v;
    }
  }
#pragma unroll
  for (int h = 0; h < 4; ++h) sm[h] = wave_sum(sm[h]);
  if (lane == 0) {
#pragma unroll
    for (int h = 0; h < 4; ++h) sums[n * 4 + h] = sm[h];
  }
}

__global__ __launch_bounds__(256) void k_gat1_agg(
    const int* __restrict__ csr_src, const int* __restrict__ indptr,
    const float* __restrict__ ex, const float* __restrict__ sums,
    const float* __restrict__ hlin, const float* __restrict__ b1,
    float* __restrict__ h1out) {
  int n = blockIdx.x;
  int j = threadIdx.x;
  int hh = j >> 6;
  int s0 = indptr[n], s1 = indptr[n + 1];
  float inv = 1.f / (sums[n * 4 + hh] + 1e-16f);
  float acc = 0.f;
  for (int e = s0; e < s1; ++e) {
    int s = csr_src[e];
    float a = ex[(size_t)e * 4 + hh] * inv;
    acc = fmaf(a, hlin[(size_t)s * C1_ + j], acc);
  }
  float o = acc + b1[j];
  h1out[(size_t)n * C1_ + j] = o > 0.f ? o : expm1f(o);
}

// ---------------- GAT layer 2 ----------------
__global__ __launch_bounds__(256) void k_gat2_lin(
    const float* __restrict__ h1out, const float* __restrict__ W2,
    const float* __restrict__ as2, const float* __restrict__ ad2,
    float* __restrict__ hlin2, float* __restrict__ als, float* __restrict__ ald) {
  int w = threadIdx.x >> 6, lane = threadIdx.x & 63;
  int n = blockIdx.x * 4 + w;
  __shared__ float sx[4][C1_];
  for (int k = lane; k < C1_; k += 64) sx[w][k] = h1out[(size_t)n * C1_ + k];
  __syncthreads();
  float acc = 0.f;
#pragma unroll 4
  for (int k = 0; k < C1_; ++k) acc = fmaf(sx[w][k], W2[k * HID_ + lane], acc);
  hlin2[(size_t)n * HID_ + lane] = acc;
  float vs = wave_sum(acc * as2[lane]);
  float vd = wave_sum(acc * ad2[lane]);
  if (lane == 0) { als[n] = vs; ald[n] = vd; }
}

__global__ __launch_bounds__(256) void k_gat2_attn(
    const int* __restrict__ csr_src, const int* __restrict__ indptr,
    const float* __restrict__ als, const float* __restrict__ ald,
    float* __restrict__ ex, float* __restrict__ sums) {
  int w = threadIdx.x >> 6, lane = threadIdx.x & 63;
  int n = blockIdx.x * 4 + w;
  int s0 = indptr[n], s1 = indptr[n + 1];
  float adv = ald[n];
  float mx = -1e30f, sm = 0.f;
  for (int e = s0 + lane; e < s1; e += 64) {
    float sc = als[csr_src[e]] + adv;
    sc = sc >= 0.f ? sc : 0.2f * sc;
    ex[e] = sc;
    mx = fmaxf(mx, sc);
  }
#pragma unroll
  for (int off = 32; off; off >>= 1) mx = fmaxf(mx, __shfl_xor(mx, off));
  for (int e = s0 + lane; e < s1; e += 64) {
    float v = __expf(ex[e] - mx);
    ex[e] = v;
    sm += v;
  }
  sm = wave_sum(sm);
  if (lane == 0) sums[n] = sm;
}

__global__ __launch_bounds__(256) void k_gat2_agg(
    const int* __restrict__ csr_src, const int* __restrict__ indptr,
    const float* __restrict__ ex, const float* __restrict__ sums,
    const float* __restrict__ hlin2, const float* __restrict__ b2,
    float* __restrict__ h2) {
  int w = threadIdx.x >> 6, lane = threadIdx.x & 63;
  int n = blockIdx.x * 4 + w;
  int s0 = indptr[n], s1 = indptr[n + 1];
  float inv = 1.f / (sums[n] + 1e-16f);
  float acc = 0.f;
  for (int e = s0; e < s1; ++e) {
    int s = csr_src[e];
    acc = fmaf(ex[e] * inv, hlin2[(size_t)s * HID_ + lane], acc);
  }
  h2[(size_t)n * HID_ + lane] = acc + b2[lane];
}

// ---------------- MFMA GRU ----------------
// bf16x3: C += Ah*Bh + Al*Bh + Ah*Bl   (Al*Bl dropped, ~2^-18 rel)
__device__ __forceinline__ void mfma3(f4v& acc, s8v ah, s8v al, s8v bh, s8v bl) {
  acc = __builtin_amdgcn_mfma_f32_16x16x32_bf16(ah, bh, acc, 0, 0, 0);
  acc = __builtin_amdgcn_mfma_f32_16x16x32_bf16(al, bh, acc, 0, 0, 0);
  acc = __builtin_amdgcn_mfma_f32_16x16x32_bf16(ah, bl, acc, 0, 0, 0);
}

// One matvec pass: C[64 edges][my 96 gate cols] += A[64][128] * W[128][384-subset]
// A in LDS as bf16 hi/lo [64][LDP_]; B packed in global fragment order (L2-resident).
// B loads are scoped per-gate so only one hi/lo pair (8 VGPRs) is live at a time
// -> live set ~ C(128) + A(32) + B(8) + addr, no scratch spill.
__device__ __forceinline__ void mfma_pass(
    const unsigned short* Ah_, const unsigned short* Al_,
    const unsigned short* __restrict__ Bh_, const unsigned short* __restrict__ Bl_,
    int w, int lane, f4v Cr[2][4], f4v Cz[2][4], f4v Cn[2][4]) {
  const int mrow = lane & 15, quad = lane >> 4;
#pragma unroll
  for (int ks = 0; ks < 4; ++ks) {
    s8v Ah[4], Al[4];
    const int aoff = mrow * LDP_ + ks * 32 + quad * 8;
#pragma unroll
    for (int mt = 0; mt < 4; ++mt) {
      Ah[mt] = *(const s8v*)(Ah_ + aoff + mt * (16 * LDP_));
      Al[mt] = *(const s8v*)(Al_ + aoff + mt * (16 * LDP_));
    }
#pragma unroll
    for (int jt = 0; jt < 2; ++jt) {
      {
        const int nt = 2 * w + jt;
        const s8v bh = *(const s8v*)(Bh_ + ((size_t)(nt * 4 + ks) * 64 + lane) * 8);
        const s8v bl = *(const s8v*)(Bl_ + ((size_t)(nt * 4 + ks) * 64 + lane) * 8);
#pragma unroll
        for (int mt = 0; mt < 4; ++mt) mfma3(Cr[jt][mt], Ah[mt], Al[mt], bh, bl);
      }
      {
        const int nt = 8 + 2 * w + jt;
        const s8v bh = *(const s8v*)(Bh_ + ((size_t)(nt * 4 + ks) * 64 + lane) * 8);
        const s8v bl = *(const s8v*)(Bl_ + ((size_t)(nt * 4 + ks) * 64 + lane) * 8);
#pragma unroll
        for (int mt = 0; mt < 4; ++mt) mfma3(Cz[jt][mt], Ah[mt], Al[mt], bh, bl);
      }
      {
        const int nt = 16 + 2 * w + jt;
        const s8v bh = *(const s8v*)(Bh_ + ((size_t)(nt * 4 + ks) * 64 + lane) * 8);
        const s8v bl = *(const s8v*)(Bl_ + ((size_t)(nt * 4 + ks) * 64 + lane) * 8);
#pragma unroll
        for (int mt = 0; mt < 4; ++mt) mfma3(Cn[jt][mt], Ah[mt], Al[mt], bh, bl);
      }
    }
  }
}

__global__ __launch_bounds__(256, 1) void k_gru_mfma(
    const float* __restrict__ h2_all, const int* __restrict__ ei,
    const unsigned short* __restrict__ pWih0h, const unsigned short* __restrict__ pWih0l,
    const unsigned short* __restrict__ pWhh0h, const unsigned short* __restrict__ pWhh0l,
    const unsigned short* __restrict__ pWih1h, const unsigned short* __restrict__ pWih1l,
    const unsigned short* __restrict__ pWhh1h, const unsigned short* __restrict__ pWhh1l,
    const float* __restrict__ bih0, const float* __restrict__ bhh0,
    const float* __restrict__ bih1, const float* __restrict__ bhh1,
    const float* __restrict__ Wd1, const float* __restrict__ bd1,
    const float* __restrict__ Wd2, const float* __restrict__ bd2,
    float* __restrict__ out) {
  __shared__ unsigned short sxh[MB_ * LDP_], sxl[MB_ * LDP_];
  __shared__ unsigned short h0h[MB_ * LDP_], h0l[MB_ * LDP_];
  __shared__ unsigned short h1h[MB_ * LDP_], h1l[MB_ * LDP_];
  __shared__ int ssrc[MB_], sdst[MB_];
  const int tid = threadIdx.x;
  const int lane = tid & 63, w = tid >> 6;
  const int col = lane & 15, quad = lane >> 4;
  const size_t i0 = (size_t)blockIdx.x * MB_;

  if (tid < MB_) { ssrc[tid] = ei[i0 + tid]; sdst[tid] = ei[E_ + i0 + tid]; }
  for (int idx = tid; idx < MB_ * LDP_; idx += 256) {
    h0h[idx] = 0; h0l[idx] = 0; h1h[idx] = 0; h1l[idx] = 0;
  }
  __syncthreads();

  const int c4 = (tid & 31) * 4;   // gather: channel group
  const int rr = tid >> 5;         // gather: edge row phase

  for (int t = 0; t < T_; ++t) {
    const float* h2 = h2_all + (size_t)t * (N_ * HID_);
    // ---- gather X = [h2[src] | h2[dst]] -> bf16 hi/lo in LDS ----
    // nontemporal: keep these streaming reads from evicting the packed
    // weights (786 KB, must stay L2-resident across all blocks).
#pragma unroll
    for (int p = 0; p < 8; ++p) {
      int e = rr + p * 8;
      int node = (c4 < 64) ? ssrc[e] : sdst[e];
      f4v v = __builtin_nontemporal_load(
          (const f4v*)(h2 + (size_t)node * HID_ + (c4 & 63)));
      ushort4 hh, ll;
      hh.x = f2bf(v.x); ll.x = f2bf(v.x - bf2f(hh.x));
      hh.y = f2bf(v.y); ll.y = f2bf(v.y - bf2f(hh.y));
      hh.z = f2bf(v.z); ll.z = f2bf(v.z - bf2f(hh.z));
      hh.w = f2bf(v.w); ll.w = f2bf(v.w - bf2f(hh.w));
      *(ushort4*)&sxh[e * LDP_ + c4] = hh;
      *(ushort4*)&sxl[e * LDP_ + c4] = ll;
    }
    __syncthreads();

    f4v Cr[2][4], Cz[2][4], Cin[2][4], Chn[2][4];
    // ---- layer 0 ----
#pragma unroll
    for (int jt = 0; jt < 2; ++jt)
#pragma unroll
      for (int mt = 0; mt < 4; ++mt) {
        Cr[jt][mt] = (f4v){0.f, 0.f, 0.f, 0.f};
        Cz[jt][mt] = (f4v){0.f, 0.f, 0.f, 0.f};
        Cin[jt][mt] = (f4v){0.f, 0.f, 0.f, 0.f};
        Chn[jt][mt] = (f4v){0.f, 0.f, 0.f, 0.f};
      }
    mfma_pass(sxh, sxl, pWih0h, pWih0l, w, lane, Cr, Cz, Cin);
    mfma_pass(h0h, h0l, pWhh0h, pWhh0l, w, lane, Cr, Cz, Chn);
    __syncthreads();   // all waves done reading h0
#pragma unroll
    for (int jt = 0; jt < 2; ++jt) {
      int cg = 32 * w + jt * 16 + col;
      float biR = bih0[cg] + bhh0[cg];
      float biZ = bih0[128 + cg] + bhh0[128 + cg];
      float biNi = bih0[256 + cg], biNh = bhh0[256 + cg];
#pragma unroll
      for (int mt = 0; mt < 4; ++mt)
#pragma unroll
        for (int reg = 0; reg < 4; ++reg) {
          int e = mt * 16 + quad * 4 + reg;
          float r = sigmoidf_(Cr[jt][mt][reg] + biR);
          float z = sigmoidf_(Cz[jt][mt][reg] + biZ);
          float n = tanhf_(Cin[jt][mt][reg] + biNi + r * (Chn[jt][mt][reg] + biNh));
          float hp = bf2f(h0h[e * LDP_ + cg]) + bf2f(h0l[e * LDP_ + cg]);
          float hv = (1.f - z) * n + z * hp;
          unsigned short hb = f2bf(hv);
          h0h[e * LDP_ + cg] = hb;
          h0l[e * LDP_ + cg] = f2bf(hv - bf2f(hb));
        }
    }
    __syncthreads();
    // ---- layer 1 ----
#pragma unroll
    for (int jt = 0; jt < 2; ++jt)
#pragma unroll
      for (int mt = 0; mt < 4; ++mt) {
        Cr[jt][mt] = (f4v){0.f, 0.f, 0.f, 0.f};
        Cz[jt][mt] = (f4v){0.f, 0.f, 0.f, 0.f};
        Cin[jt][mt] = (f4v){0.f, 0.f, 0.f, 0.f};
        Chn[jt][mt] = (f4v){0.f, 0.f, 0.f, 0.f};
      }
    mfma_pass(h0h, h0l, pWih1h, pWih1l, w, lane, Cr, Cz, Cin);
    mfma_pass(h1h, h1l, pWhh1h, pWhh1l, w, lane, Cr, Cz, Chn);
    __syncthreads();
#pragma unroll
    for (int jt = 0; jt < 2; ++jt) {
      int cg = 32 * w + jt * 16 + col;
      float biR = bih1[cg] + bhh1[cg];
      float biZ = bih1[128 + cg] + bhh1[128 + cg];
      float biNi = bih1[256 + cg], biNh = bhh1[256 + cg];
#pragma unroll
      for (int mt = 0; mt < 4; ++mt)
#pragma unroll
        for (int reg = 0; reg < 4; ++reg) {
          int e = mt * 16 + quad * 4 + reg;
          float r = sigmoidf_(Cr[jt][mt][reg] + biR);
          float z = sigmoidf_(Cz[jt][mt][reg] + biZ);
          float n = tanhf_(Cin[jt][mt][reg] + biNi + r * (Chn[jt][mt][reg] + biNh));
          float hp = bf2f(h1h[e * LDP_ + cg]) + bf2f(h1l[e * LDP_ + cg]);
          float hv = (1.f - z) * n + z * hp;
          unsigned short hb = f2bf(hv);
          h1h[e * LDP_ + cg] = hb;
          h1l[e * LDP_ + cg] = f2bf(hv - bf2f(hb));
        }
    }
    __syncthreads();
  }

  // ---- decoder: out = relu(h1 @ Wd1 + bd1) @ Wd2 + bd2 ----
  for (int ee = 0; ee < 16; ++ee) {
    int e = w * 16 + ee;
    float acc = 0.f;
#pragma unroll 8
    for (int k = 0; k < GH_; ++k) {
      float hvv = bf2f(h1h[e * LDP_ + k]) + bf2f(h1l[e * LDP_ + k]);
      acc = fmaf(hvv, Wd1[k * 64 + lane], acc);
    }
    float rv = fmaxf(acc + bd1[lane], 0.f);
    float contrib = wave_sum(rv * Wd2[lane]);
    if (lane == 0) out[i0 + e] = contrib + bd2[0];
  }
}

// ---------------- launch ----------------
extern "C" void kernel_launch(void* const* d_in, const int* in_sizes, int n_in,
                              void* d_out, int out_size, void* d_ws, size_t ws_size,
                              hipStream_t stream) {
  (void)in_sizes; (void)n_in; (void)out_size; (void)ws_size;
  const float* x_seq = (const float*)d_in[0];
  const int*   ei    = (const int*)d_in[1];
  const float* W1    = (const float*)d_in[2];
  const float* as1   = (const float*)d_in[3];
  const float* ad1   = (const float*)d_in[4];
  const float* b1    = (const float*)d_in[5];
  const float* W2    = (const float*)d_in[6];
  const float* as2   = (const float*)d_in[7];
  const float* ad2   = (const float*)d_in[8];
  const float* b2    = (const float*)d_in[9];
  const float* Wih0  = (const float*)d_in[10];
  const float* Whh0  = (const float*)d_in[11];
  const float* bih0  = (const float*)d_in[12];
  const float* bhh0  = (const float*)d_in[13];
  const float* Wih1  = (const float*)d_in[14];
  const float* Whh1  = (const float*)d_in[15];
  const float* bih1  = (const float*)d_in[16];
  const float* bhh1  = (const float*)d_in[17];
  const float* Wd1   = (const float*)d_in[18];
  const float* bd1   = (const float*)d_in[19];
  const float* Wd2   = (const float*)d_in[20];
  const float* bd2   = (const float*)d_in[21];
  float* out = (float*)d_out;

  char* p = (char*)d_ws;
  auto alloc = [&](size_t bytes) -> char* {
    char* r = p;
    p += (bytes + 255) & ~(size_t)255;
    return r;
  };
  float* h2_all = (float*)alloc((size_t)T_ * N_ * HID_ * 4);   // 41 MB
  float* hlin1  = (float*)alloc((size_t)N_ * C1_ * 4);
  float* h1out  = (float*)alloc((size_t)N_ * C1_ * 4);
  float* hlin2  = (float*)alloc((size_t)N_ * HID_ * 4);
  float* als1   = (float*)alloc((size_t)N_ * 4 * 4);
  float* ald1   = (float*)alloc((size_t)N_ * 4 * 4);
  float* sums1  = (float*)alloc((size_t)N_ * 4 * 4);
  float* als2   = (float*)alloc((size_t)N_ * 4);
  float* ald2   = (float*)alloc((size_t)N_ * 4);
  float* sums2  = (float*)alloc((size_t)N_ * 4);
  float* ex1    = (float*)alloc((size_t)ETOT_ * 4 * 4);
  float* ex2    = (float*)alloc((size_t)ETOT_ * 4);
  unsigned short* pWih0h = (unsigned short*)alloc(NPACK_ * 2);
  unsigned short* pWih0l = (unsigned short*)alloc(NPACK_ * 2);
  unsigned short* pWhh0h = (unsigned short*)alloc(NPACK_ * 2);
  unsigned short* pWhh0l = (unsigned short*)alloc(NPACK_ * 2);
  unsigned short* pWih1h = (unsigned short*)alloc(NPACK_ * 2);
  unsigned short* pWih1l = (unsigned short*)alloc(NPACK_ * 2);
  unsigned short* pWhh1h = (unsigned short*)alloc(NPACK_ * 2);
  unsigned short* pWhh1l = (unsigned short*)alloc(NPACK_ * 2);
  int* counts   = (int*)alloc((size_t)N_ * 4);
  int* indptr   = (int*)alloc((size_t)(N_ + 1) * 4);
  int* cursors  = (int*)alloc((size_t)N_ * 4);
  int* csr      = (int*)alloc((size_t)ETOT_ * 4);

  (void)hipMemsetAsync(counts, 0, (size_t)N_ * 4, stream);

  k_hist<<<(ETOT_ + 255) / 256, 256, 0, stream>>>(ei, counts);
  k_scan<<<1, 1024, 0, stream>>>(counts, indptr);
  k_copy<<<(N_ + 255) / 256, 256, 0, stream>>>(indptr, cursors);
  k_scatter<<<(ETOT_ + 255) / 256, 256, 0, stream>>>(ei, cursors, csr);
  const int pb = (NPACK_ + 255) / 256;
  k_packW<<<pb, 256, 0, stream>>>(Wih0, pWih0h, pWih0l);
  k_packW<<<pb, 256, 0, stream>>>(Whh0, pWhh0h, pWhh0l);
  k_packW<<<pb, 256, 0, stream>>>(Wih1, pWih1h, pWih1l);
  k_packW<<<pb, 256, 0, stream>>>(Whh1, pWhh1h, pWhh1l);

  for (int t = 0; t < T_; ++t) {
    const float* xt = x_seq + (size_t)t * N_ * FIN_;
    float* h2t = h2_all + (size_t)t * N_ * HID_;
    k_gat1_lin<<<N_, 256, 0, stream>>>(xt, W1, as1, ad1, hlin1, als1, ald1);
    k_gat1_attn<<<N_ / 4, 256, 0, stream>>>(csr, indptr, als1, ald1, ex1, sums1);
    k_gat1_agg<<<N_, 256, 0, stream>>>(csr, indptr, ex1, sums1, hlin1, b1, h1out);
    k_gat2_lin<<<N_ / 4, 256, 0, stream>>>(h1out, W2, as2, ad2, hlin2, als2, ald2);
    k_gat2_attn<<<N_ / 4, 256, 0, stream>>>(csr, indptr, als2, ald2, ex2, sums2);
    k_gat2_agg<<<N_ / 4, 256, 0, stream>>>(csr, indptr, ex2, sums2, hlin2, b2, h2t);
  }
  k_gru_mfma<<<E_ / MB_, 256, 0, stream>>>(
      h2_all, ei,
      pWih0h, pWih0l, pWhh0h, pWhh0l, pWih1h, pWih1l, pWhh1h, pWhh1l,
      bih0, bhh0, bih1, bhh1, Wd1, bd1, Wd2, bd2, out);
}

// Round 6
// 7791.575 us; speedup vs baseline: 2.2347x; 1.2024x over previous
//
#include <hip/hip_runtime.h>
#include <math.h>

#define T_ 8
#define N_ 20000
#define E_ 320000
#define ETOT_ (E_ + N_)
#define FIN_ 32
#define C1_ 256   // HEADS*HID
#define HID_ 64
#define G3_ 384   // 3*GH
#define GH_ 128
#define MB_ 64    // edges per block in fused GRU
#define LDP_ 136  // padded inner dim (bf16 elems); 272 B row stride keeps 16-B align for ds_read_b128
#define NPACK_ (24 * 4 * 64 * 8)   // packed weight elems per matrix

typedef __attribute__((ext_vector_type(8))) short s8v;
typedef __attribute__((ext_vector_type(4))) float f4v;   // native vector (MFMA acc + nt loads)

// ---------------- helpers ----------------
__device__ __forceinline__ float wave_sum(float v) {
#pragma unroll
  for (int off = 32; off; off >>= 1) v += __shfl_down(v, off);
  return v;
}
__device__ __forceinline__ float sigmoidf_(float x) { return 1.f / (1.f + __expf(-x)); }
__device__ __forceinline__ float tanhf_(float x) {
  float e2 = __expf(2.f * x);
  return 1.f - 2.f / (e2 + 1.f);
}
__device__ __forceinline__ unsigned short f2bf(float f) {
  union { float f; unsigned int u; } v; v.f = f;
  unsigned int r = v.u + 0x7FFFu + ((v.u >> 16) & 1u);   // RNE
  return (unsigned short)(r >> 16);
}
__device__ __forceinline__ float bf2f(unsigned short h) {
  union { unsigned int u; float f; } v; v.u = ((unsigned int)h) << 16;
  return v.f;
}
__device__ __forceinline__ void edge_sd(const int* ei, int e, int& s, int& d) {
  if (e < E_) { s = ei[e]; d = ei[E_ + e]; }
  else { s = e - E_; d = e - E_; }
}

// ---------------- CSR build (by dst) ----------------
__global__ void k_hist(const int* __restrict__ ei, int* __restrict__ counts) {
  int e = blockIdx.x * 256 + threadIdx.x;
  if (e >= ETOT_) return;
  int s, d; edge_sd(ei, e, s, d);
  atomicAdd(&counts[d], 1);
}

__global__ void k_scan(const int* __restrict__ counts, int* __restrict__ indptr) {
  __shared__ int tmp[1024];
  __shared__ int carry;
  int tid = threadIdx.x;
  if (tid == 0) { carry = 0; indptr[0] = 0; }
  __syncthreads();
  for (int base = 0; base < N_; base += 1024) {
    int i = base + tid;
    int v = (i < N_) ? counts[i] : 0;
    tmp[tid] = v;
    __syncthreads();
    for (int off = 1; off < 1024; off <<= 1) {
      int add = (tid >= off) ? tmp[tid - off] : 0;
      __syncthreads();
      tmp[tid] += add;
      __syncthreads();
    }
    if (i < N_) indptr[i + 1] = carry + tmp[tid];
    __syncthreads();
    if (tid == 1023) carry += tmp[1023];
    __syncthreads();
  }
}

__global__ void k_copy(const int* __restrict__ indptr, int* __restrict__ cursors) {
  int i = blockIdx.x * 256 + threadIdx.x;
  if (i < N_) cursors[i] = indptr[i];
}

__global__ void k_scatter(const int* __restrict__ ei, int* __restrict__ cursors,
                          int* __restrict__ csr_src) {
  int e = blockIdx.x * 256 + threadIdx.x;
  if (e >= ETOT_) return;
  int s, d; edge_sd(ei, e, s, d);
  int pos = atomicAdd(&cursors[d], 1);
  csr_src[pos] = s;
}

// ---------------- weight pack: W[384][128] fp32 -> B-fragment-ordered bf16 hi/lo ----
// flat idx = ((nt*4 + ks)*64 + lane)*8 + j ;  value = W[nt*16 + (lane&15)][ks*32 + (lane>>4)*8 + j]
__global__ void k_packW(const float* __restrict__ W, unsigned short* __restrict__ Bh,
                        unsigned short* __restrict__ Bl) {
  int idx = blockIdx.x * 256 + threadIdx.x;
  if (idx >= NPACK_) return;
  int j = idx & 7, lane = (idx >> 3) & 63, ks = (idx >> 9) & 3, nt = idx >> 11;
  int n = nt * 16 + (lane & 15);
  int k = ks * 32 + (lane >> 4) * 8 + j;
  float v = W[n * GH_ + k];
  unsigned short h = f2bf(v);
  Bh[idx] = h;
  Bl[idx] = f2bf(v - bf2f(h));
}

// ---------------- GAT layer 1 ----------------
__global__ __launch_bounds__(256) void k_gat1_lin(
    const float* __restrict__ x, const float* __restrict__ W1,
    const float* __restrict__ as1, const float* __restrict__ ad1,
    float* __restrict__ hlin, float* __restrict__ als, float* __restrict__ ald) {
  int n = blockIdx.x;
  int j = threadIdx.x;
  __shared__ float sx[FIN_];
  if (j < FIN_) sx[j] = x[n * FIN_ + j];
  __syncthreads();
  float acc = 0.f;
#pragma unroll
  for (int k = 0; k < FIN_; ++k) acc = fmaf(sx[k], W1[k * C1_ + j], acc);
  hlin[(size_t)n * C1_ + j] = acc;
  int h = j >> 6, c = j & 63;
  float vs = wave_sum(acc * as1[h * 64 + c]);
  float vd = wave_sum(acc * ad1[h * 64 + c]);
  if (c == 0) { als[n * 4 + h] = vs; ald[n * 4 + h] = vd; }
}

__global__ __launch_bounds__(256) void k_gat1_attn(
    const int* __restrict__ csr_src, const int* __restrict__ indptr,
    const float* __restrict__ als, const float* __restrict__ ald,
    float* __restrict__ ex, float* __restrict__ sums) {
  int w = threadIdx.x >> 6, lane = threadIdx.x & 63;
  int n = blockIdx.x * 4 + w;
  int s0 = indptr[n], s1 = indptr[n + 1];
  float adv[4], mx[4], sm[4];
#pragma unroll
  for (int h = 0; h < 4; ++h) { adv[h] = ald[n * 4 + h]; mx[h] = -1e30f; sm[h] = 0.f; }
  for (int e = s0 + lane; e < s1; e += 64) {
    int s = csr_src[e];
#pragma unroll
    for (int h = 0; h < 4; ++h) {
      float sc = als[s * 4 + h] + adv[h];
      sc = sc >= 0.f ? sc : 0.2f * sc;
      ex[(size_t)e * 4 + h] = sc;
      mx[h] = fmaxf(mx[h], sc);
    }
  }
#pragma unroll
  for (int h = 0; h < 4; ++h) {
#pragma unroll
    for (int off = 32; off; off >>= 1) mx[h] = fmaxf(mx[h], __shfl_xor(mx[h], off));
  }
  for (int e = s0 + lane; e < s1; e += 64) {
#pragma unroll
    for (int h = 0; h < 4; ++h) {
      float v = __expf(ex[(size_t)e * 4 + h] - mx[h]);
      ex[(size_t)e * 4 + h] = v;
      sm[h] += v;
    }
  }
#pragma unroll
  for (int h = 0; h < 4; ++h) sm[h] = wave_sum(sm[h]);
  if (lane == 0) {
#pragma unroll
    for (int h = 0; h < 4; ++h) sums[n * 4 + h] = sm[h];
  }
}

__global__ __launch_bounds__(256) void k_gat1_agg(
    const int* __restrict__ csr_src, const int* __restrict__ indptr,
    const float* __restrict__ ex, const float* __restrict__ sums,
    const float* __restrict__ hlin, const float* __restrict__ b1,
    float* __restrict__ h1out) {
  int n = blockIdx.x;
  int j = threadIdx.x;
  int hh = j >> 6;
  int s0 = indptr[n], s1 = indptr[n + 1];
  float inv = 1.f / (sums[n * 4 + hh] + 1e-16f);
  float acc = 0.f;
  for (int e = s0; e < s1; ++e) {
    int s = csr_src[e];
    float a = ex[(size_t)e * 4 + hh] * inv;
    acc = fmaf(a, hlin[(size_t)s * C1_ + j], acc);
  }
  float o = acc + b1[j];
  h1out[(size_t)n * C1_ + j] = o > 0.f ? o : expm1f(o);
}

// ---------------- GAT layer 2 ----------------
__global__ __launch_bounds__(256) void k_gat2_lin(
    const float* __restrict__ h1out, const float* __restrict__ W2,
    const float* __restrict__ as2, const float* __restrict__ ad2,
    float* __restrict__ hlin2, float* __restrict__ als, float* __restrict__ ald) {
  int w = threadIdx.x >> 6, lane = threadIdx.x & 63;
  int n = blockIdx.x * 4 + w;
  __shared__ float sx[4][C1_];
  for (int k = lane; k < C1_; k += 64) sx[w][k] = h1out[(size_t)n * C1_ + k];
  __syncthreads();
  float acc = 0.f;
#pragma unroll 4
  for (int k = 0; k < C1_; ++k) acc = fmaf(sx[w][k], W2[k * HID_ + lane], acc);
  hlin2[(size_t)n * HID_ + lane] = acc;
  float vs = wave_sum(acc * as2[lane]);
  float vd = wave_sum(acc * ad2[lane]);
  if (lane == 0) { als[n] = vs; ald[n] = vd; }
}

__global__ __launch_bounds__(256) void k_gat2_attn(
    const int* __restrict__ csr_src, const int* __restrict__ indptr,
    const float* __restrict__ als, const float* __restrict__ ald,
    float* __restrict__ ex, float* __restrict__ sums) {
  int w = threadIdx.x >> 6, lane = threadIdx.x & 63;
  int n = blockIdx.x * 4 + w;
  int s0 = indptr[n], s1 = indptr[n + 1];
  float adv = ald[n];
  float mx = -1e30f, sm = 0.f;
  for (int e = s0 + lane; e < s1; e += 64) {
    float sc = als[csr_src[e]] + adv;
    sc = sc >= 0.f ? sc : 0.2f * sc;
    ex[e] = sc;
    mx = fmaxf(mx, sc);
  }
#pragma unroll
  for (int off = 32; off; off >>= 1) mx = fmaxf(mx, __shfl_xor(mx, off));
  for (int e = s0 + lane; e < s1; e += 64) {
    float v = __expf(ex[e] - mx);
    ex[e] = v;
    sm += v;
  }
  sm = wave_sum(sm);
  if (lane == 0) sums[n] = sm;
}

__global__ __launch_bounds__(256) void k_gat2_agg(
    const int* __restrict__ csr_src, const int* __restrict__ indptr,
    const float* __restrict__ ex, const float* __restrict__ sums,
    const float* __restrict__ hlin2, const float* __restrict__ b2,
    float* __restrict__ h2) {
  int w = threadIdx.x >> 6, lane = threadIdx.x & 63;
  int n = blockIdx.x * 4 + w;
  int s0 = indptr[n], s1 = indptr[n + 1];
  float inv = 1.f / (sums[n] + 1e-16f);
  float acc = 0.f;
  for (int e = s0; e < s1; ++e) {
    int s = csr_src[e];
    acc = fmaf(ex[e] * inv, hlin2[(size_t)s * HID_ + lane], acc);
  }
  h2[(size_t)n * HID_ + lane] = acc + b2[lane];
}

// ---------------- MFMA GRU ----------------
// bf16x3: C += Ah*Bh + Al*Bh + Ah*Bl   (Al*Bl dropped, ~2^-18 rel)
__device__ __forceinline__ void mfma3(f4v& acc, s8v ah, s8v al, s8v bh, s8v bl) {
  acc = __builtin_amdgcn_mfma_f32_16x16x32_bf16(ah, bh, acc, 0, 0, 0);
  acc = __builtin_amdgcn_mfma_f32_16x16x32_bf16(al, bh, acc, 0, 0, 0);
  acc = __builtin_amdgcn_mfma_f32_16x16x32_bf16(ah, bl, acc, 0, 0, 0);
}

// One matvec pass, 8-wave version: wave w owns ONE 16-col N-tile per gate
// (r: nt=w, z: nt=8+w, n: nt=16+w). C[64 edges][16 cols] per gate.
// Accumulators: 3 x 4 x f4v = 48 VGPRs -> no spill even with hoisted B loads.
__device__ __forceinline__ void mfma_pass(
    const unsigned short* Ah_, const unsigned short* Al_,
    const unsigned short* __restrict__ Bh_, const unsigned short* __restrict__ Bl_,
    int w, int lane, f4v Cr[4], f4v Cz[4], f4v Cn[4]) {
  const int mrow = lane & 15, quad = lane >> 4;
#pragma unroll
  for (int ks = 0; ks < 4; ++ks) {
    s8v Ah[4], Al[4];
    const int aoff = mrow * LDP_ + ks * 32 + quad * 8;
#pragma unroll
    for (int mt = 0; mt < 4; ++mt) {
      Ah[mt] = *(const s8v*)(Ah_ + aoff + mt * (16 * LDP_));
      Al[mt] = *(const s8v*)(Al_ + aoff + mt * (16 * LDP_));
    }
    {
      const int nt = w;
      const s8v bh = *(const s8v*)(Bh_ + ((size_t)(nt * 4 + ks) * 64 + lane) * 8);
      const s8v bl = *(const s8v*)(Bl_ + ((size_t)(nt * 4 + ks) * 64 + lane) * 8);
#pragma unroll
      for (int mt = 0; mt < 4; ++mt) mfma3(Cr[mt], Ah[mt], Al[mt], bh, bl);
    }
    {
      const int nt = 8 + w;
      const s8v bh = *(const s8v*)(Bh_ + ((size_t)(nt * 4 + ks) * 64 + lane) * 8);
      const s8v bl = *(const s8v*)(Bl_ + ((size_t)(nt * 4 + ks) * 64 + lane) * 8);
#pragma unroll
      for (int mt = 0; mt < 4; ++mt) mfma3(Cz[mt], Ah[mt], Al[mt], bh, bl);
    }
    {
      const int nt = 16 + w;
      const s8v bh = *(const s8v*)(Bh_ + ((size_t)(nt * 4 + ks) * 64 + lane) * 8);
      const s8v bl = *(const s8v*)(Bl_ + ((size_t)(nt * 4 + ks) * 64 + lane) * 8);
#pragma unroll
      for (int mt = 0; mt < 4; ++mt) mfma3(Cn[mt], Ah[mt], Al[mt], bh, bl);
    }
  }
}

__global__ __launch_bounds__(512, 1) void k_gru_mfma(
    const float* __restrict__ h2_all, const int* __restrict__ ei,
    const unsigned short* __restrict__ pWih0h, const unsigned short* __restrict__ pWih0l,
    const unsigned short* __restrict__ pWhh0h, const unsigned short* __restrict__ pWhh0l,
    const unsigned short* __restrict__ pWih1h, const unsigned short* __restrict__ pWih1l,
    const unsigned short* __restrict__ pWhh1h, const unsigned short* __restrict__ pWhh1l,
    const float* __restrict__ bih0, const float* __restrict__ bhh0,
    const float* __restrict__ bih1, const float* __restrict__ bhh1,
    const float* __restrict__ Wd1, const float* __restrict__ bd1,
    const float* __restrict__ Wd2, const float* __restrict__ bd2,
    float* __restrict__ out) {
  __shared__ unsigned short sxh[MB_ * LDP_], sxl[MB_ * LDP_];
  __shared__ unsigned short h0h[MB_ * LDP_], h0l[MB_ * LDP_];
  __shared__ unsigned short h1h[MB_ * LDP_], h1l[MB_ * LDP_];
  __shared__ int ssrc[MB_], sdst[MB_];
  const int tid = threadIdx.x;
  const int lane = tid & 63, w = tid >> 6;   // w in 0..7
  const int col = lane & 15, quad = lane >> 4;
  const size_t i0 = (size_t)blockIdx.x * MB_;

  if (tid < MB_) { ssrc[tid] = ei[i0 + tid]; sdst[tid] = ei[E_ + i0 + tid]; }
  for (int idx = tid; idx < MB_ * LDP_; idx += 512) {
    h0h[idx] = 0; h0l[idx] = 0; h1h[idx] = 0; h1l[idx] = 0;
  }
  __syncthreads();

  const int c4 = (tid & 31) * 4;   // gather: channel group (0..124)
  const int rr = tid >> 5;         // gather: edge row phase (0..15)
  const int cg = w * 16 + col;     // this lane's gate-col (0..127)

  for (int t = 0; t < T_; ++t) {
    const float* h2 = h2_all + (size_t)t * (N_ * HID_);
    // ---- gather X = [h2[src] | h2[dst]] -> bf16 hi/lo in LDS ----
    // nontemporal: keep the streaming gathers from evicting the packed
    // weights (786 KB, must stay L2-resident across all blocks).
#pragma unroll
    for (int p = 0; p < 4; ++p) {
      int e = rr + p * 16;
      int node = (c4 < 64) ? ssrc[e] : sdst[e];
      f4v v = __builtin_nontemporal_load(
          (const f4v*)(h2 + (size_t)node * HID_ + (c4 & 63)));
      ushort4 hh, ll;
      hh.x = f2bf(v.x); ll.x = f2bf(v.x - bf2f(hh.x));
      hh.y = f2bf(v.y); ll.y = f2bf(v.y - bf2f(hh.y));
      hh.z = f2bf(v.z); ll.z = f2bf(v.z - bf2f(hh.z));
      hh.w = f2bf(v.w); ll.w = f2bf(v.w - bf2f(hh.w));
      *(ushort4*)&sxh[e * LDP_ + c4] = hh;
      *(ushort4*)&sxl[e * LDP_ + c4] = ll;
    }
    __syncthreads();

    f4v Cr[4], Cz[4], Cin[4], Chn[4];
    // ---- layer 0 ----
#pragma unroll
    for (int mt = 0; mt < 4; ++mt) {
      Cr[mt] = (f4v){0.f, 0.f, 0.f, 0.f};
      Cz[mt] = (f4v){0.f, 0.f, 0.f, 0.f};
      Cin[mt] = (f4v){0.f, 0.f, 0.f, 0.f};
      Chn[mt] = (f4v){0.f, 0.f, 0.f, 0.f};
    }
    mfma_pass(sxh, sxl, pWih0h, pWih0l, w, lane, Cr, Cz, Cin);
    mfma_pass(h0h, h0l, pWhh0h, pWhh0l, w, lane, Cr, Cz, Chn);
    __syncthreads();   // all waves done reading h0
    {
      float biR = bih0[cg] + bhh0[cg];
      float biZ = bih0[128 + cg] + bhh0[128 + cg];
      float biNi = bih0[256 + cg], biNh = bhh0[256 + cg];
#pragma unroll
      for (int mt = 0; mt < 4; ++mt)
#pragma unroll
        for (int reg = 0; reg < 4; ++reg) {
          int e = mt * 16 + quad * 4 + reg;
          float r = sigmoidf_(Cr[mt][reg] + biR);
          float z = sigmoidf_(Cz[mt][reg] + biZ);
          float n = tanhf_(Cin[mt][reg] + biNi + r * (Chn[mt][reg] + biNh));
          float hp = bf2f(h0h[e * LDP_ + cg]) + bf2f(h0l[e * LDP_ + cg]);
          float hv = (1.f - z) * n + z * hp;
          unsigned short hb = f2bf(hv);
          h0h[e * LDP_ + cg] = hb;
          h0l[e * LDP_ + cg] = f2bf(hv - bf2f(hb));
        }
    }
    __syncthreads();
    // ---- layer 1 ----
#pragma unroll
    for (int mt = 0; mt < 4; ++mt) {
      Cr[mt] = (f4v){0.f, 0.f, 0.f, 0.f};
      Cz[mt] = (f4v){0.f, 0.f, 0.f, 0.f};
      Cin[mt] = (f4v){0.f, 0.f, 0.f, 0.f};
      Chn[mt] = (f4v){0.f, 0.f, 0.f, 0.f};
    }
    mfma_pass(h0h, h0l, pWih1h, pWih1l, w, lane, Cr, Cz, Cin);
    mfma_pass(h1h, h1l, pWhh1h, pWhh1l, w, lane, Cr, Cz, Chn);
    __syncthreads();
    {
      float biR = bih1[cg] + bhh1[cg];
      float biZ = bih1[128 + cg] + bhh1[128 + cg];
      float biNi = bih1[256 + cg], biNh = bhh1[256 + cg];
#pragma unroll
      for (int mt = 0; mt < 4; ++mt)
#pragma unroll
        for (int reg = 0; reg < 4; ++reg) {
          int e = mt * 16 + quad * 4 + reg;
          float r = sigmoidf_(Cr[mt][reg] + biR);
          float z = sigmoidf_(Cz[mt][reg] + biZ);
          float n = tanhf_(Cin[mt][reg] + biNi + r * (Chn[mt][reg] + biNh));
          float hp = bf2f(h1h[e * LDP_ + cg]) + bf2f(h1l[e * LDP_ + cg]);
          float hv = (1.f - z) * n + z * hp;
          unsigned short hb = f2bf(hv);
          h1h[e * LDP_ + cg] = hb;
          h1l[e * LDP_ + cg] = f2bf(hv - bf2f(hb));
        }
    }
    __syncthreads();
  }

  // ---- decoder: out = relu(h1 @ Wd1 + bd1) @ Wd2 + bd2 ----
  for (int ee = 0; ee < 8; ++ee) {
    int e = w * 8 + ee;
    float acc = 0.f;
#pragma unroll 8
    for (int k = 0; k < GH_; ++k) {
      float hvv = bf2f(h1h[e * LDP_ + k]) + bf2f(h1l[e * LDP_ + k]);
      acc = fmaf(hvv, Wd1[k * 64 + lane], acc);
    }
    float rv = fmaxf(acc + bd1[lane], 0.f);
    float contrib = wave_sum(rv * Wd2[lane]);
    if (lane == 0) out[i0 + e] = contrib + bd2[0];
  }
}

// ---------------- launch ----------------
extern "C" void kernel_launch(void* const* d_in, const int* in_sizes, int n_in,
                              void* d_out, int out_size, void* d_ws, size_t ws_size,
                              hipStream_t stream) {
  (void)in_sizes; (void)n_in; (void)out_size; (void)ws_size;
  const float* x_seq = (const float*)d_in[0];
  const int*   ei    = (const int*)d_in[1];
  const float* W1    = (const float*)d_in[2];
  const float* as1   = (const float*)d_in[3];
  const float* ad1   = (const float*)d_in[4];
  const float* b1    = (const float*)d_in[5];
  const float* W2    = (const float*)d_in[6];
  const float* as2   = (const float*)d_in[7];
  const float* ad2   = (const float*)d_in[8];
  const float* b2    = (const float*)d_in[9];
  const float* Wih0  = (const float*)d_in[10];
  const float* Whh0  = (const float*)d_in[11];
  const float* bih0  = (const float*)d_in[12];
  const float* bhh0  = (const float*)d_in[13];
  const float* Wih1  = (const float*)d_in[14];
  const float* Whh1  = (const float*)d_in[15];
  const float* bih1  = (const float*)d_in[16];
  const float* bhh1  = (const float*)d_in[17];
  const float* Wd1   = (const float*)d_in[18];
  const float* bd1   = (const float*)d_in[19];
  const float* Wd2   = (const float*)d_in[20];
  const float* bd2   = (const float*)d_in[21];
  float* out = (float*)d_out;

  char* p = (char*)d_ws;
  auto alloc = [&](size_t bytes) -> char* {
    char* r = p;
    p += (bytes + 255) & ~(size_t)255;
    return r;
  };
  float* h2_all = (float*)alloc((size_t)T_ * N_ * HID_ * 4);   // 41 MB
  float* hlin1  = (float*)alloc((size_t)N_ * C1_ * 4);
  float* h1out  = (float*)alloc((size_t)N_ * C1_ * 4);
  float* hlin2  = (float*)alloc((size_t)N_ * HID_ * 4);
  float* als1   = (float*)alloc((size_t)N_ * 4 * 4);
  float* ald1   = (float*)alloc((size_t)N_ * 4 * 4);
  float* sums1  = (float*)alloc((size_t)N_ * 4 * 4);
  float* als2   = (float*)alloc((size_t)N_ * 4);
  float* ald2   = (float*)alloc((size_t)N_ * 4);
  float* sums2  = (float*)alloc((size_t)N_ * 4);
  float* ex1    = (float*)alloc((size_t)ETOT_ * 4 * 4);
  float* ex2    = (float*)alloc((size_t)ETOT_ * 4);
  unsigned short* pWih0h = (unsigned short*)alloc(NPACK_ * 2);
  unsigned short* pWih0l = (unsigned short*)alloc(NPACK_ * 2);
  unsigned short* pWhh0h = (unsigned short*)alloc(NPACK_ * 2);
  unsigned short* pWhh0l = (unsigned short*)alloc(NPACK_ * 2);
  unsigned short* pWih1h = (unsigned short*)alloc(NPACK_ * 2);
  unsigned short* pWih1l = (unsigned short*)alloc(NPACK_ * 2);
  unsigned short* pWhh1h = (unsigned short*)alloc(NPACK_ * 2);
  unsigned short* pWhh1l = (unsigned short*)alloc(NPACK_ * 2);
  int* counts   = (int*)alloc((size_t)N_ * 4);
  int* indptr   = (int*)alloc((size_t)(N_ + 1) * 4);
  int* cursors  = (int*)alloc((size_t)N_ * 4);
  int* csr      = (int*)alloc((size_t)ETOT_ * 4);

  (void)hipMemsetAsync(counts, 0, (size_t)N_ * 4, stream);

  k_hist<<<(ETOT_ + 255) / 256, 256, 0, stream>>>(ei, counts);
  k_scan<<<1, 1024, 0, stream>>>(counts, indptr);
  k_copy<<<(N_ + 255) / 256, 256, 0, stream>>>(indptr, cursors);
  k_scatter<<<(ETOT_ + 255) / 256, 256, 0, stream>>>(ei, cursors, csr);
  const int pb = (NPACK_ + 255) / 256;
  k_packW<<<pb, 256, 0, stream>>>(Wih0, pWih0h, pWih0l);
  k_packW<<<pb, 256, 0, stream>>>(Whh0, pWhh0h, pWhh0l);
  k_packW<<<pb, 256, 0, stream>>>(Wih1, pWih1h, pWih1l);
  k_packW<<<pb, 256, 0, stream>>>(Whh1, pWhh1h, pWhh1l);

  for (int t = 0; t < T_; ++t) {
    const float* xt = x_seq + (size_t)t * N_ * FIN_;
    float* h2t = h2_all + (size_t)t * N_ * HID_;
    k_gat1_lin<<<N_, 256, 0, stream>>>(xt, W1, as1, ad1, hlin1, als1, ald1);
    k_gat1_attn<<<N_ / 4, 256, 0, stream>>>(csr, indptr, als1, ald1, ex1, sums1);
    k_gat1_agg<<<N_, 256, 0, stream>>>(csr, indptr, ex1, sums1, hlin1, b1, h1out);
    k_gat2_lin<<<N_ / 4, 256, 0, stream>>>(h1out, W2, as2, ad2, hlin2, als2, ald2);
    k_gat2_attn<<<N_ / 4, 256, 0, stream>>>(csr, indptr, als2, ald2, ex2, sums2);
    k_gat2_agg<<<N_ / 4, 256, 0, stream>>>(csr, indptr, ex2, sums2, hlin2, b2, h2t);
  }
  k_gru_mfma<<<E_ / MB_, 512, 0, stream>>>(
      h2_all, ei,
      pWih0h, pWih0l, pWhh0h, pWhh0l, pWih1h, pWih1l, pWhh1h, pWhh1l,
      bih0, bhh0, bih1, bhh1, Wd1, bd1, Wd2, bd2, out);
}

// Round 7
// 7548.140 us; speedup vs baseline: 2.3068x; 1.0323x over previous
//
#include <hip/hip_runtime.h>
#include <hip/hip_fp16.h>
#include <math.h>

#define T_ 8
#define N_ 20000
#define E_ 320000
#define ETOT_ (E_ + N_)
#define FIN_ 32
#define C1_ 256   // HEADS*HID
#define HID_ 64
#define G3_ 384   // 3*GH
#define GH_ 128
#define MB_ 64    // edges per block in fused GRU
#define LDP_ 136  // padded inner dim (elems); 272 B row stride = 17*16 B -> all frags 16-B aligned
#define NPACK_ (24 * 4 * 64 * 8)   // packed weight elems per matrix

typedef __attribute__((ext_vector_type(8))) short s8v;
typedef __attribute__((ext_vector_type(8))) _Float16 h8v;
typedef __attribute__((ext_vector_type(4))) float f4v;

// ---------------- helpers ----------------
__device__ __forceinline__ float wave_sum(float v) {
#pragma unroll
  for (int off = 32; off; off >>= 1) v += __shfl_down(v, off);
  return v;
}
__device__ __forceinline__ float sigmoidf_(float x) { return 1.f / (1.f + __expf(-x)); }
__device__ __forceinline__ float tanhf_(float x) {
  float e2 = __expf(2.f * x);
  return 1.f - 2.f / (e2 + 1.f);
}
__device__ __forceinline__ unsigned short f2bf(float f) {
  union { float f; unsigned int u; } v; v.f = f;
  unsigned int r = v.u + 0x7FFFu + ((v.u >> 16) & 1u);   // RNE
  return (unsigned short)(r >> 16);
}
__device__ __forceinline__ float bf2f(unsigned short h) {
  union { unsigned int u; float f; } v; v.u = ((unsigned int)h) << 16;
  return v.f;
}
__device__ __forceinline__ unsigned short f2h(float f) {
  return __half_as_ushort(__float2half_rn(f));
}
__device__ __forceinline__ float h2f(unsigned short u) {
  return __half2float(__ushort_as_half(u));
}
__device__ __forceinline__ void edge_sd(const int* ei, int e, int& s, int& d) {
  if (e < E_) { s = ei[e]; d = ei[E_ + e]; }
  else { s = e - E_; d = e - E_; }
}

// ---------------- CSR build (by dst) ----------------
__global__ void k_hist(const int* __restrict__ ei, int* __restrict__ counts) {
  int e = blockIdx.x * 256 + threadIdx.x;
  if (e >= ETOT_) return;
  int s, d; edge_sd(ei, e, s, d);
  atomicAdd(&counts[d], 1);
}

__global__ void k_scan(const int* __restrict__ counts, int* __restrict__ indptr) {
  __shared__ int tmp[1024];
  __shared__ int carry;
  int tid = threadIdx.x;
  if (tid == 0) { carry = 0; indptr[0] = 0; }
  __syncthreads();
  for (int base = 0; base < N_; base += 1024) {
    int i = base + tid;
    int v = (i < N_) ? counts[i] : 0;
    tmp[tid] = v;
    __syncthreads();
    for (int off = 1; off < 1024; off <<= 1) {
      int add = (tid >= off) ? tmp[tid - off] : 0;
      __syncthreads();
      tmp[tid] += add;
      __syncthreads();
    }
    if (i < N_) indptr[i + 1] = carry + tmp[tid];
    __syncthreads();
    if (tid == 1023) carry += tmp[1023];
    __syncthreads();
  }
}

__global__ void k_copy(const int* __restrict__ indptr, int* __restrict__ cursors) {
  int i = blockIdx.x * 256 + threadIdx.x;
  if (i < N_) cursors[i] = indptr[i];
}

__global__ void k_scatter(const int* __restrict__ ei, int* __restrict__ cursors,
                          int* __restrict__ csr_src) {
  int e = blockIdx.x * 256 + threadIdx.x;
  if (e >= ETOT_) return;
  int s, d; edge_sd(ei, e, s, d);
  int pos = atomicAdd(&cursors[d], 1);
  csr_src[pos] = s;
}

// ---------------- weight pack: W[384][128] fp32 -> B-fragment order ----------------
// flat idx = ((nt*4 + ks)*64 + lane)*8 + j ; value = W[nt*16 + (lane&15)][ks*32 + (lane>>4)*8 + j]
__global__ void k_packW(const float* __restrict__ W, unsigned short* __restrict__ Bh,
                        unsigned short* __restrict__ Bl) {   // bf16 hi/lo
  int idx = blockIdx.x * 256 + threadIdx.x;
  if (idx >= NPACK_) return;
  int j = idx & 7, lane = (idx >> 3) & 63, ks = (idx >> 9) & 3, nt = idx >> 11;
  int n = nt * 16 + (lane & 15);
  int k = ks * 32 + (lane >> 4) * 8 + j;
  float v = W[n * GH_ + k];
  unsigned short h = f2bf(v);
  Bh[idx] = h;
  Bl[idx] = f2bf(v - bf2f(h));
}

__global__ void k_packW16(const float* __restrict__ W, unsigned short* __restrict__ Bh,
                          unsigned short* __restrict__ Bl) {  // fp16 hi/lo
  int idx = blockIdx.x * 256 + threadIdx.x;
  if (idx >= NPACK_) return;
  int j = idx & 7, lane = (idx >> 3) & 63, ks = (idx >> 9) & 3, nt = idx >> 11;
  int n = nt * 16 + (lane & 15);
  int k = ks * 32 + (lane >> 4) * 8 + j;
  float v = W[n * GH_ + k];
  unsigned short h = f2h(v);
  Bh[idx] = h;
  Bl[idx] = f2h(v - h2f(h));
}

// ---------------- GAT layer 1 ----------------
__global__ __launch_bounds__(256) void k_gat1_lin(
    const float* __restrict__ x, const float* __restrict__ W1,
    const float* __restrict__ as1, const float* __restrict__ ad1,
    float* __restrict__ hlin, float* __restrict__ als, float* __restrict__ ald) {
  int n = blockIdx.x;
  int j = threadIdx.x;
  __shared__ float sx[FIN_];
  if (j < FIN_) sx[j] = x[n * FIN_ + j];
  __syncthreads();
  float acc = 0.f;
#pragma unroll
  for (int k = 0; k < FIN_; ++k) acc = fmaf(sx[k], W1[k * C1_ + j], acc);
  hlin[(size_t)n * C1_ + j] = acc;
  int h = j >> 6, c = j & 63;
  float vs = wave_sum(acc * as1[h * 64 + c]);
  float vd = wave_sum(acc * ad1[h * 64 + c]);
  if (c == 0) { als[n * 4 + h] = vs; ald[n * 4 + h] = vd; }
}

__global__ __launch_bounds__(256) void k_gat1_attn(
    const int* __restrict__ csr_src, const int* __restrict__ indptr,
    const float* __restrict__ als, const float* __restrict__ ald,
    float* __restrict__ ex, float* __restrict__ sums) {
  int w = threadIdx.x >> 6, lane = threadIdx.x & 63;
  int n = blockIdx.x * 4 + w;
  int s0 = indptr[n], s1 = indptr[n + 1];
  float adv[4], mx[4], sm[4];
#pragma unroll
  for (int h = 0; h < 4; ++h) { adv[h] = ald[n * 4 + h]; mx[h] = -1e30f; sm[h] = 0.f; }
  for (int e = s0 + lane; e < s1; e += 64) {
    int s = csr_src[e];
#pragma unroll
    for (int h = 0; h < 4; ++h) {
      float sc = als[s * 4 + h] + adv[h];
      sc = sc >= 0.f ? sc : 0.2f * sc;
      ex[(size_t)e * 4 + h] = sc;
      mx[h] = fmaxf(mx[h], sc);
    }
  }
#pragma unroll
  for (int h = 0; h < 4; ++h) {
#pragma unroll
    for (int off = 32; off; off >>= 1) mx[h] = fmaxf(mx[h], __shfl_xor(mx[h], off));
  }
  for (int e = s0 + lane; e < s1; e += 64) {
#pragma unroll
    for (int h = 0; h < 4; ++h) {
      float v = __expf(ex[(size_t)e * 4 + h] - mx[h]);
      ex[(size_t)e * 4 + h] = v;
      sm[h] += v;
    }
  }
#pragma unroll
  for (int h = 0; h < 4; ++h) sm[h] = wave_sum(sm[h]);
  if (lane == 0) {
#pragma unroll
    for (int h = 0; h < 4; ++h) sums[n * 4 + h] = sm[h];
  }
}

__global__ __launch_bounds__(256) void k_gat1_agg(
    const int* __restrict__ csr_src, const int* __restrict__ indptr,
    const float* __restrict__ ex, const float* __restrict__ sums,
    const float* __restrict__ hlin, const float* __restrict__ b1,
    float* __restrict__ h1out) {
  int n = blockIdx.x;
  int j = threadIdx.x;
  int hh = j >> 6;
  int s0 = indptr[n], s1 = indptr[n + 1];
  float inv = 1.f / (sums[n * 4 + hh] + 1e-16f);
  float acc = 0.f;
  for (int e = s0; e < s1; ++e) {
    int s = csr_src[e];
    float a = ex[(size_t)e * 4 + hh] * inv;
    acc = fmaf(a, hlin[(size_t)s * C1_ + j], acc);
  }
  float o = acc + b1[j];
  h1out[(size_t)n * C1_ + j] = o > 0.f ? o : expm1f(o);
}

// ---------------- GAT layer 2 ----------------
__global__ __launch_bounds__(256) void k_gat2_lin(
    const float* __restrict__ h1out, const float* __restrict__ W2,
    const float* __restrict__ as2, const float* __restrict__ ad2,
    float* __restrict__ hlin2, float* __restrict__ als, float* __restrict__ ald) {
  int w = threadIdx.x >> 6, lane = threadIdx.x & 63;
  int n = blockIdx.x * 4 + w;
  __shared__ float sx[4][C1_];
  for (int k = lane; k < C1_; k += 64) sx[w][k] = h1out[(size_t)n * C1_ + k];
  __syncthreads();
  float acc = 0.f;
#pragma unroll 4
  for (int k = 0; k < C1_; ++k) acc = fmaf(sx[w][k], W2[k * HID_ + lane], acc);
  hlin2[(size_t)n * HID_ + lane] = acc;
  float vs = wave_sum(acc * as2[lane]);
  float vd = wave_sum(acc * ad2[lane]);
  if (lane == 0) { als[n] = vs; ald[n] = vd; }
}

__global__ __launch_bounds__(256) void k_gat2_attn(
    const int* __restrict__ csr_src, const int* __restrict__ indptr,
    const float* __restrict__ als, const float* __restrict__ ald,
    float* __restrict__ ex, float* __restrict__ sums) {
  int w = threadIdx.x >> 6, lane = threadIdx.x & 63;
  int n = blockIdx.x * 4 + w;
  int s0 = indptr[n], s1 = indptr[n + 1];
  float adv = ald[n];
  float mx = -1e30f, sm = 0.f;
  for (int e = s0 + lane; e < s1; e += 64) {
    float sc = als[csr_src[e]] + adv;
    sc = sc >= 0.f ? sc : 0.2f * sc;
    ex[e] = sc;
    mx = fmaxf(mx, sc);
  }
#pragma unroll
  for (int off = 32; off; off >>= 1) mx = fmaxf(mx, __shfl_xor(mx, off));
  for (int e = s0 + lane; e < s1; e += 64) {
    float v = __expf(ex[e] - mx);
    ex[e] = v;
    sm += v;
  }
  sm = wave_sum(sm);
  if (lane == 0) sums[n] = sm;
}

// writes h2 as fp16 (2.56 MB/t slice -> L2-resident together with the packed weights)
__global__ __launch_bounds__(256) void k_gat2_agg(
    const int* __restrict__ csr_src, const int* __restrict__ indptr,
    const float* __restrict__ ex, const float* __restrict__ sums,
    const float* __restrict__ hlin2, const float* __restrict__ b2,
    unsigned short* __restrict__ h2f16) {
  int w = threadIdx.x >> 6, lane = threadIdx.x & 63;
  int n = blockIdx.x * 4 + w;
  int s0 = indptr[n], s1 = indptr[n + 1];
  float inv = 1.f / (sums[n] + 1e-16f);
  float acc = 0.f;
  for (int e = s0; e < s1; ++e) {
    int s = csr_src[e];
    acc = fmaf(ex[e] * inv, hlin2[(size_t)s * HID_ + lane], acc);
  }
  h2f16[(size_t)n * HID_ + lane] = f2h(acc + b2[lane]);
}

// ---------------- MFMA GRU ----------------
// bf16x3: C += Ah*Bh + Al*Bh + Ah*Bl   (Al*Bl dropped, ~2^-18 rel)
__device__ __forceinline__ void mfma3(f4v& acc, s8v ah, s8v al, s8v bh, s8v bl) {
  acc = __builtin_amdgcn_mfma_f32_16x16x32_bf16(ah, bh, acc, 0, 0, 0);
  acc = __builtin_amdgcn_mfma_f32_16x16x32_bf16(al, bh, acc, 0, 0, 0);
  acc = __builtin_amdgcn_mfma_f32_16x16x32_bf16(ah, bl, acc, 0, 0, 0);
}
// fp16 X pass: C += A*(Bh+Bl) with A fp16 (2^-11), W split to fp16 hi/lo
__device__ __forceinline__ void mfma2h(f4v& acc, h8v a, h8v bh, h8v bl) {
  acc = __builtin_amdgcn_mfma_f32_16x16x32_f16(a, bh, acc, 0, 0, 0);
  acc = __builtin_amdgcn_mfma_f32_16x16x32_f16(a, bl, acc, 0, 0, 0);
}

// bf16x3 pass: wave w owns one 16-col N-tile per gate (r: w, z: 8+w, n: 16+w)
__device__ __forceinline__ void mfma_pass(
    const unsigned short* Ah_, const unsigned short* Al_,
    const unsigned short* __restrict__ Bh_, const unsigned short* __restrict__ Bl_,
    int w, int lane, f4v Cr[4], f4v Cz[4], f4v Cn[4]) {
  const int mrow = lane & 15, quad = lane >> 4;
#pragma unroll
  for (int ks = 0; ks < 4; ++ks) {
    s8v Ah[4], Al[4];
    const int aoff = mrow * LDP_ + ks * 32 + quad * 8;
#pragma unroll
    for (int mt = 0; mt < 4; ++mt) {
      Ah[mt] = *(const s8v*)(Ah_ + aoff + mt * (16 * LDP_));
      Al[mt] = *(const s8v*)(Al_ + aoff + mt * (16 * LDP_));
    }
    {
      const int nt = w;
      const s8v bh = *(const s8v*)(Bh_ + ((size_t)(nt * 4 + ks) * 64 + lane) * 8);
      const s8v bl = *(const s8v*)(Bl_ + ((size_t)(nt * 4 + ks) * 64 + lane) * 8);
#pragma unroll
      for (int mt = 0; mt < 4; ++mt) mfma3(Cr[mt], Ah[mt], Al[mt], bh, bl);
    }
    {
      const int nt = 8 + w;
      const s8v bh = *(const s8v*)(Bh_ + ((size_t)(nt * 4 + ks) * 64 + lane) * 8);
      const s8v bl = *(const s8v*)(Bl_ + ((size_t)(nt * 4 + ks) * 64 + lane) * 8);
#pragma unroll
      for (int mt = 0; mt < 4; ++mt) mfma3(Cz[mt], Ah[mt], Al[mt], bh, bl);
    }
    {
      const int nt = 16 + w;
      const s8v bh = *(const s8v*)(Bh_ + ((size_t)(nt * 4 + ks) * 64 + lane) * 8);
      const s8v bl = *(const s8v*)(Bl_ + ((size_t)(nt * 4 + ks) * 64 + lane) * 8);
#pragma unroll
      for (int mt = 0; mt < 4; ++mt) mfma3(Cn[mt], Ah[mt], Al[mt], bh, bl);
    }
  }
}

// fp16 X pass (gi0): A = gathered X fp16 in LDS, B = fp16 hi/lo packed Wih0
__device__ __forceinline__ void mfma_pass_x(
    const unsigned short* X_,
    const unsigned short* __restrict__ Bh_, const unsigned short* __restrict__ Bl_,
    int w, int lane, f4v Cr[4], f4v Cz[4], f4v Cn[4]) {
  const int mrow = lane & 15, quad = lane >> 4;
#pragma unroll
  for (int ks = 0; ks < 4; ++ks) {
    h8v A[4];
    const int aoff = mrow * LDP_ + ks * 32 + quad * 8;
#pragma unroll
    for (int mt = 0; mt < 4; ++mt) A[mt] = *(const h8v*)(X_ + aoff + mt * (16 * LDP_));
    {
      const int nt = w;
      const h8v bh = *(const h8v*)(Bh_ + ((size_t)(nt * 4 + ks) * 64 + lane) * 8);
      const h8v bl = *(const h8v*)(Bl_ + ((size_t)(nt * 4 + ks) * 64 + lane) * 8);
#pragma unroll
      for (int mt = 0; mt < 4; ++mt) mfma2h(Cr[mt], A[mt], bh, bl);
    }
    {
      const int nt = 8 + w;
      const h8v bh = *(const h8v*)(Bh_ + ((size_t)(nt * 4 + ks) * 64 + lane) * 8);
      const h8v bl = *(const h8v*)(Bl_ + ((size_t)(nt * 4 + ks) * 64 + lane) * 8);
#pragma unroll
      for (int mt = 0; mt < 4; ++mt) mfma2h(Cz[mt], A[mt], bh, bl);
    }
    {
      const int nt = 16 + w;
      const h8v bh = *(const h8v*)(Bh_ + ((size_t)(nt * 4 + ks) * 64 + lane) * 8);
      const h8v bl = *(const h8v*)(Bl_ + ((size_t)(nt * 4 + ks) * 64 + lane) * 8);
#pragma unroll
      for (int mt = 0; mt < 4; ++mt) mfma2h(Cn[mt], A[mt], bh, bl);
    }
  }
}

__global__ __launch_bounds__(512, 1) void k_gru_mfma(
    const unsigned short* __restrict__ h2_all, const int* __restrict__ ei,
    const unsigned short* __restrict__ pWih0h, const unsigned short* __restrict__ pWih0l,
    const unsigned short* __restrict__ pWhh0h, const unsigned short* __restrict__ pWhh0l,
    const unsigned short* __restrict__ pWih1h, const unsigned short* __restrict__ pWih1l,
    const unsigned short* __restrict__ pWhh1h, const unsigned short* __restrict__ pWhh1l,
    const float* __restrict__ bih0, const float* __restrict__ bhh0,
    const float* __restrict__ bih1, const float* __restrict__ bhh1,
    const float* __restrict__ Wd1, const float* __restrict__ bd1,
    const float* __restrict__ Wd2, const float* __restrict__ bd2,
    float* __restrict__ out) {
  __shared__ unsigned short sxh[MB_ * LDP_];                 // fp16 X
  __shared__ unsigned short h0h[MB_ * LDP_], h0l[MB_ * LDP_];
  __shared__ unsigned short h1h[MB_ * LDP_], h1l[MB_ * LDP_];
  __shared__ int ssrc[MB_], sdst[MB_];
  const int tid = threadIdx.x;
  const int lane = tid & 63, w = tid >> 6;   // w in 0..7
  const int col = lane & 15, quad = lane >> 4;
  const size_t i0 = (size_t)blockIdx.x * MB_;

  if (tid < MB_) { ssrc[tid] = ei[i0 + tid]; sdst[tid] = ei[E_ + i0 + tid]; }
  for (int idx = tid; idx < MB_ * LDP_; idx += 512) {
    h0h[idx] = 0; h0l[idx] = 0; h1h[idx] = 0; h1l[idx] = 0;
  }
  __syncthreads();

  const int g8 = tid & 15;    // gather: 8-channel group (0..15)
  const int er = tid >> 4;    // gather: edge row (0..31), 2 rows per thread
  const int cg = w * 16 + col;

  for (int t = 0; t < T_; ++t) {
    const unsigned short* h2 = h2_all + (size_t)t * (N_ * HID_);
    // ---- gather X = [h2[src] | h2[dst]] fp16 -> LDS (16-B loads, cached) ----
#pragma unroll
    for (int p = 0; p < 2; ++p) {
      int e = er + p * 32;
      int node = (g8 < 8) ? ssrc[e] : sdst[e];
      s8v v = *(const s8v*)(h2 + (size_t)node * HID_ + (g8 & 7) * 8);
      *(s8v*)&sxh[e * LDP_ + g8 * 8] = v;
    }
    __syncthreads();

    f4v Cr[4], Cz[4], Cin[4], Chn[4];
    // ---- layer 0 ----
#pragma unroll
    for (int mt = 0; mt < 4; ++mt) {
      Cr[mt] = (f4v){0.f, 0.f, 0.f, 0.f};
      Cz[mt] = (f4v){0.f, 0.f, 0.f, 0.f};
      Cin[mt] = (f4v){0.f, 0.f, 0.f, 0.f};
      Chn[mt] = (f4v){0.f, 0.f, 0.f, 0.f};
    }
    mfma_pass_x(sxh, pWih0h, pWih0l, w, lane, Cr, Cz, Cin);
    mfma_pass(h0h, h0l, pWhh0h, pWhh0l, w, lane, Cr, Cz, Chn);
    __syncthreads();   // all waves done reading h0
    {
      float biR = bih0[cg] + bhh0[cg];
      float biZ = bih0[128 + cg] + bhh0[128 + cg];
      float biNi = bih0[256 + cg], biNh = bhh0[256 + cg];
#pragma unroll
      for (int mt = 0; mt < 4; ++mt)
#pragma unroll
        for (int reg = 0; reg < 4; ++reg) {
          int e = mt * 16 + quad * 4 + reg;
          float r = sigmoidf_(Cr[mt][reg] + biR);
          float z = sigmoidf_(Cz[mt][reg] + biZ);
          float n = tanhf_(Cin[mt][reg] + biNi + r * (Chn[mt][reg] + biNh));
          float hp = bf2f(h0h[e * LDP_ + cg]) + bf2f(h0l[e * LDP_ + cg]);
          float hv = (1.f - z) * n + z * hp;
          unsigned short hb = f2bf(hv);
          h0h[e * LDP_ + cg] = hb;
          h0l[e * LDP_ + cg] = f2bf(hv - bf2f(hb));
        }
    }
    __syncthreads();
    // ---- layer 1 ----
#pragma unroll
    for (int mt = 0; mt < 4; ++mt) {
      Cr[mt] = (f4v){0.f, 0.f, 0.f, 0.f};
      Cz[mt] = (f4v){0.f, 0.f, 0.f, 0.f};
      Cin[mt] = (f4v){0.f, 0.f, 0.f, 0.f};
      Chn[mt] = (f4v){0.f, 0.f, 0.f, 0.f};
    }
    mfma_pass(h0h, h0l, pWih1h, pWih1l, w, lane, Cr, Cz, Cin);
    mfma_pass(h1h, h1l, pWhh1h, pWhh1l, w, lane, Cr, Cz, Chn);
    __syncthreads();
    {
      float biR = bih1[cg] + bhh1[cg];
      float biZ = bih1[128 + cg] + bhh1[128 + cg];
      float biNi = bih1[256 + cg], biNh = bhh1[256 + cg];
#pragma unroll
      for (int mt = 0; mt < 4; ++mt)
#pragma unroll
        for (int reg = 0; reg < 4; ++reg) {
          int e = mt * 16 + quad * 4 + reg;
          float r = sigmoidf_(Cr[mt][reg] + biR);
          float z = sigmoidf_(Cz[mt][reg] + biZ);
          float n = tanhf_(Cin[mt][reg] + biNi + r * (Chn[mt][reg] + biNh));
          float hp = bf2f(h1h[e * LDP_ + cg]) + bf2f(h1l[e * LDP_ + cg]);
          float hv = (1.f - z) * n + z * hp;
          unsigned short hb = f2bf(hv);
          h1h[e * LDP_ + cg] = hb;
          h1l[e * LDP_ + cg] = f2bf(hv - bf2f(hb));
        }
    }
    __syncthreads();
  }

  // ---- decoder: out = relu(h1 @ Wd1 + bd1) @ Wd2 + bd2 ----
  for (int ee = 0; ee < 8; ++ee) {
    int e = w * 8 + ee;
    float acc = 0.f;
#pragma unroll 8
    for (int k = 0; k < GH_; ++k) {
      float hvv = bf2f(h1h[e * LDP_ + k]) + bf2f(h1l[e * LDP_ + k]);
      acc = fmaf(hvv, Wd1[k * 64 + lane], acc);
    }
    float rv = fmaxf(acc + bd1[lane], 0.f);
    float contrib = wave_sum(rv * Wd2[lane]);
    if (lane == 0) out[i0 + e] = contrib + bd2[0];
  }
}

// ---------------- launch ----------------
extern "C" void kernel_launch(void* const* d_in, const int* in_sizes, int n_in,
                              void* d_out, int out_size, void* d_ws, size_t ws_size,
                              hipStream_t stream) {
  (void)in_sizes; (void)n_in; (void)out_size; (void)ws_size;
  const float* x_seq = (const float*)d_in[0];
  const int*   ei    = (const int*)d_in[1];
  const float* W1    = (const float*)d_in[2];
  const float* as1   = (const float*)d_in[3];
  const float* ad1   = (const float*)d_in[4];
  const float* b1    = (const float*)d_in[5];
  const float* W2    = (const float*)d_in[6];
  const float* as2   = (const float*)d_in[7];
  const float* ad2   = (const float*)d_in[8];
  const float* b2    = (const float*)d_in[9];
  const float* Wih0  = (const float*)d_in[10];
  const float* Whh0  = (const float*)d_in[11];
  const float* bih0  = (const float*)d_in[12];
  const float* bhh0  = (const float*)d_in[13];
  const float* Wih1  = (const float*)d_in[14];
  const float* Whh1  = (const float*)d_in[15];
  const float* bih1  = (const float*)d_in[16];
  const float* bhh1  = (const float*)d_in[17];
  const float* Wd1   = (const float*)d_in[18];
  const float* bd1   = (const float*)d_in[19];
  const float* Wd2   = (const float*)d_in[20];
  const float* bd2   = (const float*)d_in[21];
  float* out = (float*)d_out;

  char* p = (char*)d_ws;
  auto alloc = [&](size_t bytes) -> char* {
    char* r = p;
    p += (bytes + 255) & ~(size_t)255;
    return r;
  };
  unsigned short* h2_all = (unsigned short*)alloc((size_t)T_ * N_ * HID_ * 2);  // fp16, 20.5 MB
  float* hlin1  = (float*)alloc((size_t)N_ * C1_ * 4);
  float* h1out  = (float*)alloc((size_t)N_ * C1_ * 4);
  float* hlin2  = (float*)alloc((size_t)N_ * HID_ * 4);
  float* als1   = (float*)alloc((size_t)N_ * 4 * 4);
  float* ald1   = (float*)alloc((size_t)N_ * 4 * 4);
  float* sums1  = (float*)alloc((size_t)N_ * 4 * 4);
  float* als2   = (float*)alloc((size_t)N_ * 4);
  float* ald2   = (float*)alloc((size_t)N_ * 4);
  float* sums2  = (float*)alloc((size_t)N_ * 4);
  float* ex1    = (float*)alloc((size_t)ETOT_ * 4 * 4);
  float* ex2    = (float*)alloc((size_t)ETOT_ * 4);
  unsigned short* pWih0h = (unsigned short*)alloc(NPACK_ * 2);   // fp16
  unsigned short* pWih0l = (unsigned short*)alloc(NPACK_ * 2);   // fp16
  unsigned short* pWhh0h = (unsigned short*)alloc(NPACK_ * 2);
  unsigned short* pWhh0l = (unsigned short*)alloc(NPACK_ * 2);
  unsigned short* pWih1h = (unsigned short*)alloc(NPACK_ * 2);
  unsigned short* pWih1l = (unsigned short*)alloc(NPACK_ * 2);
  unsigned short* pWhh1h = (unsigned short*)alloc(NPACK_ * 2);
  unsigned short* pWhh1l = (unsigned short*)alloc(NPACK_ * 2);
  int* counts   = (int*)alloc((size_t)N_ * 4);
  int* indptr   = (int*)alloc((size_t)(N_ + 1) * 4);
  int* cursors  = (int*)alloc((size_t)N_ * 4);
  int* csr      = (int*)alloc((size_t)ETOT_ * 4);

  (void)hipMemsetAsync(counts, 0, (size_t)N_ * 4, stream);

  k_hist<<<(ETOT_ + 255) / 256, 256, 0, stream>>>(ei, counts);
  k_scan<<<1, 1024, 0, stream>>>(counts, indptr);
  k_copy<<<(N_ + 255) / 256, 256, 0, stream>>>(indptr, cursors);
  k_scatter<<<(ETOT_ + 255) / 256, 256, 0, stream>>>(ei, cursors, csr);
  const int pb = (NPACK_ + 255) / 256;
  k_packW16<<<pb, 256, 0, stream>>>(Wih0, pWih0h, pWih0l);
  k_packW<<<pb, 256, 0, stream>>>(Whh0, pWhh0h, pWhh0l);
  k_packW<<<pb, 256, 0, stream>>>(Wih1, pWih1h, pWih1l);
  k_packW<<<pb, 256, 0, stream>>>(Whh1, pWhh1h, pWhh1l);

  for (int t = 0; t < T_; ++t) {
    const float* xt = x_seq + (size_t)t * N_ * FIN_;
    unsigned short* h2t = h2_all + (size_t)t * N_ * HID_;
    k_gat1_lin<<<N_, 256, 0, stream>>>(xt, W1, as1, ad1, hlin1, als1, ald1);
    k_gat1_attn<<<N_ / 4, 256, 0, stream>>>(csr, indptr, als1, ald1, ex1, sums1);
    k_gat1_agg<<<N_, 256, 0, stream>>>(csr, indptr, ex1, sums1, hlin1, b1, h1out);
    k_gat2_lin<<<N_ / 4, 256, 0, stream>>>(h1out, W2, as2, ad2, hlin2, als2, ald2);
    k_gat2_attn<<<N_ / 4, 256, 0, stream>>>(csr, indptr, als2, ald2, ex2, sums2);
    k_gat2_agg<<<N_ / 4, 256, 0, stream>>>(csr, indptr, ex2, sums2, hlin2, b2, h2t);
  }
  k_gru_mfma<<<E_ / MB_, 512, 0, stream>>>(
      h2_all, ei,
      pWih0h, pWih0l, pWhh0h, pWhh0l, pWih1h, pWih1l, pWhh1h, pWhh1l,
      bih0, bhh0, bih1, bhh1, Wd1, bd1, Wd2, bd2, out);
}